// Round 7
// baseline (660.635 us; speedup 1.0000x reference)
//
#include <hip/hip_runtime.h>
#include <math.h>

#define TPB 256

typedef __attribute__((ext_vector_type(8))) short bf16x8;
typedef __attribute__((ext_vector_type(4))) float f32x4;
typedef __attribute__((ext_vector_type(16))) float f32x16;
typedef __attribute__((ext_vector_type(2))) float f32x2;

// ---------------- workspace layout ----------------
// aux (fp32), float offsets:
#define OFF_PN2   0          // 256
#define OFF_GN2   256        // 256
#define OFF_GATE  512        // 256
#define OFF_TEMP  768        // 1
#define OFF_WEFF  1024       // 2560
#define OFF_W1T   3584       // 2400 fp32: w1t[tap<75][oc<32]
// bf16 weight tables (byte offsets):
#define OFF_W2T_BYTES 737280ul    // 9*64*32   bf16
#define OFF_W3T_BYTES 786432ul    // 9*128*64  bf16
#define OFF_W4T_BYTES 983040ul    // 9*256*128 bf16
#define OFF_EWT_BYTES 2097152ul   // ewt[n=256][k=16384] bf16 = 8 MiB
// post-stage bf16 tables:
#define OFF_NFWT_BYTES 10485760ul // nfwt[n=256][k=256] bf16 = 128 KiB
#define OFF_PJD_BYTES  10616832ul // protos[j][d] bf16
#define OFF_GJD_BYTES  10747904ul // grid[j][d] bf16
#define OFF_PTB_BYTES  10878976ul // protosT[d][j] bf16
// big regions (byte offsets):
#define OFF_A_BYTES   12582912ul  // h4c ping buffer: 2048 img x 32KB = 64 MiB
#define OFF_B_BYTES   (OFF_A_BYTES + 67108864ul)   // h2c: 4096 img x 8KB = 32 MiB
#define OFF_Z0_BYTES  (OFF_B_BYTES + 33554432ul)   // z0: 4096x256 f32 = 4 MiB
// total ~112 MiB

// ---------------- bf16 helpers ----------------
__device__ __forceinline__ float bf2f(ushort u) {
  return __uint_as_float(((unsigned)u) << 16);
}
__device__ __forceinline__ ushort f2bf(float f) {   // RNE
  unsigned x = __float_as_uint(f);
  return (ushort)((x + 0x7fffu + ((x >> 16) & 1u)) >> 16);
}
__device__ __forceinline__ unsigned pack2(float a, float b) {
  return (unsigned)f2bf(a) | ((unsigned)f2bf(b) << 16);
}

// async global->LDS, 16B per lane; lds dest = wave-uniform base + lane*16
__device__ __forceinline__ void gload_lds16(const ushort* g, ushort* l) {
  __builtin_amdgcn_global_load_lds(
      (const __attribute__((address_space(1))) unsigned int*)g,
      (__attribute__((address_space(3))) unsigned int*)l, 16, 0, 0);
}

// ---------------- block reductions ----------------
__device__ __forceinline__ float block_sum(float v, float* red) {
  #pragma unroll
  for (int off = 32; off > 0; off >>= 1) v += __shfl_down(v, off, 64);
  int wid = threadIdx.x >> 6;
  __syncthreads();
  if ((threadIdx.x & 63) == 0) red[wid] = v;
  __syncthreads();
  return red[0] + red[1] + red[2] + red[3];
}

// ---------------- k_init: merged setup + prep + prep2 + trans ------------------
// blocks [0,1024):    trans  (enc_w -> ewt bf16 transpose)
// blocks [1024,2176): prep   (conv weight tables)
// blocks [2176,2432): setup  (norms, gate, temp, weff, z0 zero)
// blocks [2432,2688): prep2  (post-stage bf16 tables)
__global__ void __launch_bounds__(256) k_init(
    const float* __restrict__ ew,    ushort* __restrict__ ewt,
    const float* __restrict__ w1,    const float* __restrict__ w2,
    const float* __restrict__ w3,    const float* __restrict__ w4,
    float* __restrict__ w1t, ushort* __restrict__ w2t,
    ushort* __restrict__ w3t, ushort* __restrict__ w4t,
    const float* __restrict__ protos, const float* __restrict__ gridp,
    const float* __restrict__ gate_logits, const float* __restrict__ temp_raw,
    const float* __restrict__ clf_w, float* __restrict__ ws,
    float* __restrict__ z0,
    const float* __restrict__ nfw, ushort* __restrict__ nfwt,
    ushort* __restrict__ pjd, ushort* __restrict__ gjd,
    ushort* __restrict__ ptb) {
  __shared__ float tile[64][65];
  __shared__ float red[4];
  const int bx = blockIdx.x, t = threadIdx.x;

  if (bx < 1024) {                 // ---- trans ----
    int kb = bx & 255, nb = bx >> 8;
    #pragma unroll
    for (int i = 0; i < 16; ++i) {
      int idx = t + i*256, k = idx >> 6, n = idx & 63;
      tile[k][n] = ew[(size_t)(kb*64 + k)*256 + nb*64 + n];
    }
    __syncthreads();
    #pragma unroll
    for (int i = 0; i < 16; ++i) {
      int idx = t + i*256, n = idx >> 6, k = idx & 63;
      ewt[(size_t)(nb*64 + n)*16384 + kb*64 + k] = f2bf(tile[k][n]);
    }
    return;
  }
  if (bx < 2176) {                 // ---- prep ----
    int idx = (bx - 1024)*256 + t;
    if (idx < 2400) {
      int tap = idx >> 5, oc = idx & 31;
      w1t[idx] = w1[oc*75 + tap];
    }
    if (idx < 18432) {
      int tap = idx >> 11, r = idx & 2047, oc = r >> 5, ic = r & 31;
      w2t[idx] = f2bf(w2[oc*288 + ic*9 + tap]);
    }
    if (idx < 73728) {
      int tap = idx >> 13, r = idx & 8191, oc = r >> 6, ic = r & 63;
      w3t[idx] = f2bf(w3[oc*576 + ic*9 + tap]);
    }
    if (idx < 294912) {
      int tap = idx >> 15, r = idx & 32767, oc = r >> 7, ic = r & 127;
      w4t[idx] = f2bf(w4[oc*1152 + ic*9 + tap]);
    }
    return;
  }
  if (bx < 2432) {                 // ---- setup ----
    int b = bx - 2176;
    #pragma unroll
    for (int u = 0; u < 16; ++u) z0[(size_t)u*65536 + b*256 + t] = 0.f;
    float pv = protos[b*256 + t];
    float gv = gridp [b*256 + t];
    float sp = block_sum(pv*pv, red);
    float sg = block_sum(gv*gv, red);
    if (t == 0) {
      ws[OFF_PN2 + b] = sp;
      ws[OFF_GN2 + b] = sg;
      ws[OFF_GATE + b] = 1.f/(1.f + expf(-gate_logits[b]));
    }
    if (b == 0) {
      for (int i = t; i < 2560; i += TPB) {
        int d = i/10, c = i%10;
        ws[OFF_WEFF + i] = clf_w[d*10+c] + clf_w[(256+d)*10+c]
                         + clf_w[(512+d)*10+c] + clf_w[(768+d)*10+c];
      }
      if (t == 0) {
        float s = 1.f/(1.f + expf(-temp_raw[0]));
        ws[OFF_TEMP] = s*(1.f - 0.001f) + 0.001f;
      }
    }
    return;
  }
  {                                // ---- prep2 ----
    int idx = (bx - 2432)*256 + t;   // 65536
    int a = idx >> 8, b = idx & 255;
    nfwt[idx] = f2bf(nfw[b*256 + a]);     // [n][k] = nfw[k][n]
    pjd [idx] = f2bf(protos[idx]);        // [j][d]
    gjd [idx] = f2bf(gridp[idx]);         // [j][d]
    ptb [idx] = f2bf(protos[b*256 + a]);  // [d][j] = protos[j][d]
  }
}

// ---------------- conv1+conv2 fused v4: minimal LDS (xs only, 23.1 KB) ----------
__global__ void __launch_bounds__(256) k_conv12(const float* __restrict__ x,
    const float* __restrict__ w1t, const float* __restrict__ b1,
    const ushort* __restrict__ w2t, const float* __restrict__ b2,
    ushort* __restrict__ h2c) {
  __shared__ ushort xs[17*17*40];   // 23120 B only
  int b = blockIdx.x, t = threadIdx.x;
  for (int i = t; i < 5780; i += TPB) ((unsigned*)xs)[i] = 0u;
  const float* xb = x + (size_t)b*3072;

  if (t < 225) {               // conv1: one px per thread, all 32 oc, packed f32
    int oy = t/15, ox = t%15;
    f32x2 acc[16];
    #pragma unroll
    for (int o = 0; o < 16; ++o) acc[o] = *(const f32x2*)&b1[2*o];
    for (int ic = 0; ic < 3; ++ic) {
      const int icb = ic*1024;
      #pragma unroll
      for (int ky = 0; ky < 5; ++ky) {
        int iy = 2*oy - 1 + ky;
        bool rok = (unsigned)iy < 32u;
        int rbase = icb + (rok ? iy*32 : 0);
        #pragma unroll
        for (int kx = 0; kx < 5; ++kx) {
          int ix = 2*ox - 1 + kx;
          bool ok = rok && ((unsigned)ix < 32u);
          float xv = xb[rbase + (ok ? ix : 0)];
          xv = ok ? xv : 0.f;
          f32x2 xv2 = {xv, xv};
          const float* wrow = &w1t[(ic*25 + ky*5 + kx)*32];   // wave-uniform -> s_load
          #pragma unroll
          for (int g = 0; g < 8; ++g) {
            f32x2 wlo = {wrow[4*g+0], wrow[4*g+1]};
            f32x2 whi = {wrow[4*g+2], wrow[4*g+3]};
            acc[2*g]   += xv2*wlo;
            acc[2*g+1] += xv2*whi;
          }
        }
      }
    }
    unsigned pk[16];
    #pragma unroll
    for (int g = 0; g < 16; ++g)
      pk[g] = pack2(fmaxf(acc[g].x, 0.f), fmaxf(acc[g].y, 0.f));
    ushort* cell = &xs[((oy+1)*17 + (ox+1))*40];
    #pragma unroll
    for (int q = 0; q < 4; ++q) *(uint4*)(cell + q*8) = ((uint4*)pk)[q];
  }
  __syncthreads();

  // conv2 MFMA (swapped: oc-in-regs): wave w -> oc [w*16, w*16+16)
  const int lane = t & 63, w = t >> 6;
  const int quad = lane >> 4, row16 = lane & 15;
  f32x4 acc2[4];
  #pragma unroll
  for (int mt = 0; mt < 4; ++mt) acc2[mt] = (f32x4)0.f;
  #pragma unroll
  for (int ky = 0; ky < 3; ++ky)
    #pragma unroll
    for (int kx = 0; kx < 3; ++kx) {
      int tap = ky*3 + kx;
      bf16x8 bf = *(const bf16x8*)&w2t[tap*2048 + (w*16 + row16)*32 + quad*8];
      #pragma unroll
      for (int mt = 0; mt < 4; ++mt) {
        int px = mt*16 + row16;
        int iy = 2*(px >> 3) + ky, ix = 2*(px & 7) + kx;
        bf16x8 af = *(const bf16x8*)&xs[(iy*17 + ix)*40 + quad*8];
        acc2[mt] = __builtin_amdgcn_mfma_f32_16x16x32_bf16(bf, af, acc2[mt], 0, 0, 0);
      }
    }
  float4 bb = *(const float4*)&b2[w*16 + quad*4];
  #pragma unroll
  for (int mt = 0; mt < 4; ++mt) {
    int px = mt*16 + row16;
    uint2 dd;
    dd.x = pack2(fmaxf(acc2[mt][0] + bb.x, 0.f), fmaxf(acc2[mt][1] + bb.y, 0.f));
    dd.y = pack2(fmaxf(acc2[mt][2] + bb.z, 0.f), fmaxf(acc2[mt][3] + bb.w, 0.f));
    *(uint2*)&h2c[(size_t)b*4096 + px*64 + w*16 + quad*4] = dd;
  }
}

// ---------------- conv3+conv4 fused v13 ----------------------------------------
// conv3: v12's verified 16x16 path unchanged. conv4: 32x32x16 MFMA — doubles
// FLOP per LDS byte (kernel was LDS-BW-bound: 8 waves x 8KB reads per step-period
// = 512cy LDS vs 320cy MFMA). New wave decomp: wave = (img = w>>1, oc-half 128);
// per step 2 LDS A-reads feed 8 MFMAs (was 8 reads -> 32). Depth-2 weight ring
// (2 steps x 2 waves = 256cy cover > L2 latency) avoids v7's short-span stall.
// 32x32 fragment maps lifted from v7's conv4 (harness-verified): A/B row|col =
// lane&31, k = (lane>>5)*8+e; D col=lane&31, row=(r&3)+8*(r>>2)+4*(lane>>5).
// Regs: 128 acc + 32 ring + ~80 arch ~ 240 < 256 (launch_bounds(256,2)).
__global__ void __launch_bounds__(256, 2) k_conv34(const ushort* __restrict__ h2c,
    const float* __restrict__ b3, const float* __restrict__ b4,
    const ushort* __restrict__ w3t, const ushort* __restrict__ w4t,
    ushort* __restrict__ h4c, int img_base) {
  // xp  = [img<2][row<100][72]   (14400 ushorts, 28.8 KB)  -- conv3 input
  // h3p = [img<2][row<100][136]  (27200 ushorts, 54.4 KB)  -- aliased, conv4 input
  __shared__ __attribute__((aligned(16))) ushort buf[27200];
  ushort* xp  = buf;
  ushort* h3p = buf;
  const int bl = blockIdx.x, t = threadIdx.x;

  // ---- zero xp halo ring: 2 img x 36 rows x 9 uint4 ----
  for (int i = t; i < 648; i += 256) {
    int img = (i >= 324), r = i - img*324;
    int row = r/9, c = r - row*9;
    int rr = (row < 20) ? ((row < 10) ? row : row + 80)
                        : (((row-20) >> 1) + 1)*10 + ((row-20) & 1)*9;
    *(uint4*)&xp[img*7200 + rr*72 + c*8] = (uint4){0,0,0,0};
  }
  // ---- stage conv3 input interior (disjoint from ring; no barrier needed) ----
  #pragma unroll
  for (int u = 0; u < 4; ++u) {
    int i = t + u*256;
    int img = i >> 9, px = (i >> 3) & 63, icg = i & 7;
    bf16x8 v = *(const bf16x8*)&h2c[(size_t)(img_base + bl*2 + img)*4096 + px*64 + icg*8];
    int row = ((px >> 3) + 1)*10 + (px & 7) + 1;
    *(bf16x8*)&xp[img*7200 + row*72 + icg*8] = v;
  }
  __syncthreads();

  const int lane = t & 63, w = t >> 6;
  const int quad = lane >> 4, row16 = lane & 15;

  // conv3 per-mt LDS base offsets (ushort units); mt = img*4 + px-group
  int b3off[8], r11c[8];
  #pragma unroll
  for (int mt = 0; mt < 8; ++mt) {
    int px = (mt & 3)*16 + row16;
    int r00 = (px >> 3)*10 + (px & 7);     // halo-corner row for tap (0,0)
    int img = mt >> 2;
    b3off[mt] = img*7200  + r00*72  + quad*8;
    r11c[mt]  = img*13600 + (r00 + 11)*136;   // interior row for epilogue
  }

  // ---- conv3: wave = 32 oc (w*32, 2 frags) x 8 mt (2 img x 64 px), 16x16x32 ----
  const int ocb3 = w*32;
  f32x4 c3[8][2];
  #pragma unroll
  for (int mt = 0; mt < 8; ++mt) { c3[mt][0] = (f32x4)0.f; c3[mt][1] = (f32x4)0.f; }
  const ushort* w3b = w3t + (ocb3 + row16)*64 + quad*8;
  bf16x8 wa0 = *(const bf16x8*)(w3b);          // (tap0, ks0), oc-lo 16
  bf16x8 wa1 = *(const bf16x8*)(w3b + 1024);   // oc-hi 16
  #pragma unroll
  for (int tap = 0; tap < 9; ++tap) {
    const int t72 = ((tap/3)*10 + (tap%3))*72;     // compile-time after unroll
    #pragma unroll
    for (int ks = 0; ks < 2; ++ks) {
      // depth-1 weight prefetch; tap==8 overshoot reads workspace gap (discarded)
      const ushort* wn = w3b + ((ks == 0) ? (tap*8192 + 32) : ((tap+1)*8192));
      bf16x8 n0 = *(const bf16x8*)(wn);
      bf16x8 n1 = *(const bf16x8*)(wn + 1024);
      #pragma unroll
      for (int mt = 0; mt < 8; ++mt) {
        bf16x8 af = *(const bf16x8*)&xp[b3off[mt] + t72 + ks*32];
        c3[mt][0] = __builtin_amdgcn_mfma_f32_16x16x32_bf16(wa0, af, c3[mt][0], 0, 0, 0);
        c3[mt][1] = __builtin_amdgcn_mfma_f32_16x16x32_bf16(wa1, af, c3[mt][1], 0, 0, 0);
      }
      wa0 = n0; wa1 = n1;
    }
  }
  __syncthreads();   // ALIAS BARRIER: all xp reads done before h3p overwrites buf

  // ---- zero h3p halo ring: 2 img x 36 rows x 17 uint4 (disjoint from interior) ----
  for (int i = t; i < 1224; i += 256) {
    int img2 = (i >= 612), r = i - img2*612;
    int row = r/17, c = r - row*17;
    int rr = (row < 20) ? ((row < 10) ? row : row + 80)
                        : (((row-20) >> 1) + 1)*10 + ((row-20) & 1)*9;
    *(uint4*)&h3p[img2*13600 + rr*136 + c*8] = (uint4){0,0,0,0};
  }
  // ---- conv3 epilogue: D col=px(row16), row=oc(quad*4+r) -> h3p interior ----
  #pragma unroll
  for (int nt = 0; nt < 2; ++nt) {
    float4 bb = *(const float4*)&b3[ocb3 + nt*16 + quad*4];
    #pragma unroll
    for (int mt = 0; mt < 8; ++mt) {
      uint2 dd;
      dd.x = pack2(fmaxf(c3[mt][nt][0] + bb.x, 0.f), fmaxf(c3[mt][nt][1] + bb.y, 0.f));
      dd.y = pack2(fmaxf(c3[mt][nt][2] + bb.z, 0.f), fmaxf(c3[mt][nt][3] + bb.w, 0.f));
      *(uint2*)&h3p[r11c[mt] + ocb3 + nt*16 + quad*4] = dd;
    }
  }
  __syncthreads();

  // ---- conv4: 32x32x16; wave = (img4 = w>>1, oh = w&1 -> 128 oc);
  //      2 px-groups x 4 oc-blocks, acc = 8 x f32x16 = 128 ----
  const int half = lane >> 5, ln = lane & 31;
  const int img4 = w >> 1, oh = w & 1;
  int a4off[2];
  #pragma unroll
  for (int pg = 0; pg < 2; ++pg) {
    int px = pg*32 + ln;
    int r00 = (px >> 3)*10 + (px & 7);
    a4off[pg] = img4*13600 + r00*136 + half*8;  // + taprow*136 + ks*16
  }
  f32x16 c4[2][4];
  #pragma unroll
  for (int pg = 0; pg < 2; ++pg)
    #pragma unroll
    for (int ob = 0; ob < 4; ++ob) c4[pg][ob] = (f32x16)0.f;
  const ushort* w4base = w4t + (oh*128 + ln)*128 + half*8;  // +ob*4096 +tap*32768 +ks*16
  // depth-2 weight ring: preload steps 0 and 1
  bf16x8 wr0[4], wr1[4];
  #pragma unroll
  for (int ob = 0; ob < 4; ++ob) {
    wr0[ob] = *(const bf16x8*)(w4base + ob*4096);
    wr1[ob] = *(const bf16x8*)(w4base + ob*4096 + 16);
  }
  #pragma unroll
  for (int tap = 0; tap < 9; ++tap) {
    const int tr136 = ((tap/3)*10 + (tap%3))*136;
    #pragma unroll
    for (int ks = 0; ks < 8; ++ks) {
      const int s  = tap*8 + ks;
      const int s2 = s + 2;                    // prefetch target step
      const int t2 = s2 >> 3, k2 = s2 & 7;     // tap==9 overshoot lands in gap
      bf16x8 wnx[4];
      #pragma unroll
      for (int ob = 0; ob < 4; ++ob)
        wnx[ob] = *(const bf16x8*)(w4base + ob*4096 + t2*32768 + k2*16);
      bf16x8 xf[2];
      #pragma unroll
      for (int pg = 0; pg < 2; ++pg)
        xf[pg] = *(const bf16x8*)&h3p[a4off[pg] + tr136 + ks*16];
      if ((s & 1) == 0) {
        #pragma unroll
        for (int pg = 0; pg < 2; ++pg)
          #pragma unroll
          for (int ob = 0; ob < 4; ++ob)
            c4[pg][ob] = __builtin_amdgcn_mfma_f32_32x32x16_bf16(xf[pg], wr0[ob], c4[pg][ob], 0, 0, 0);
        #pragma unroll
        for (int ob = 0; ob < 4; ++ob) wr0[ob] = wnx[ob];
      } else {
        #pragma unroll
        for (int pg = 0; pg < 2; ++pg)
          #pragma unroll
          for (int ob = 0; ob < 4; ++ob)
            c4[pg][ob] = __builtin_amdgcn_mfma_f32_32x32x16_bf16(xf[pg], wr1[ob], c4[pg][ob], 0, 0, 0);
        #pragma unroll
        for (int ob = 0; ob < 4; ++ob) wr1[ob] = wnx[ob];
      }
    }
  }
  // ---- conv4 epilogue: D col=oc(ln), row-px = pg*32 + 8q + 4*half + (r&3);
  //      4 consecutive px per reg-quad -> uint2 into h4c[oc*64+px] (v7-verified) ----
  {
    const int ig = bl*2 + img4;               // ping-buffer row [0,2048)
    #pragma unroll
    for (int ob = 0; ob < 4; ++ob) {
      int oc = oh*128 + ob*32 + ln;
      float bv = b4[oc];
      #pragma unroll
      for (int pg = 0; pg < 2; ++pg) {
        #pragma unroll
        for (int q = 0; q < 4; ++q) {
          int px0 = pg*32 + 8*q + 4*half;
          uint2 dd;
          dd.x = pack2(fmaxf(c4[pg][ob][4*q+0] + bv, 0.f), fmaxf(c4[pg][ob][4*q+1] + bv, 0.f));
          dd.y = pack2(fmaxf(c4[pg][ob][4*q+2] + bv, 0.f), fmaxf(c4[pg][ob][4*q+3] + bv, 0.f));
          *(uint2*)&h4c[(size_t)ig*16384 + oc*64 + px0] = dd;
        }
      }
    }
  }
}

// ---------------- enc: z0 += h4c @ ewt^T, MFMA bf16, split-K=16, 128x128 tiles ------
__global__ void __launch_bounds__(256) k_enc(const ushort* __restrict__ h4c,
    const ushort* __restrict__ ewt, float* __restrict__ z0, int img_base) {
  __shared__ ushort a_s[128*64];   // 16 KB
  __shared__ ushort b_s[128*64];   // 16 KB
  const int t = threadIdx.x, bx = blockIdx.x;
  const int slice = bx & 15;
  const int mb = (bx >> 4) & 15;
  const int nb = bx >> 8;
  const int M0 = mb*128, N0 = nb*128;
  const int kbase = slice*1024;
  const int lane = t & 63, wv = t >> 6;
  const int quad = lane >> 4, row16 = lane & 15;
  const int mrow0 = (wv & 1)*64, ncol0 = (wv >> 1)*64;
  const int sr = lane >> 3, sp = lane & 7;

  f32x4 acc[4][4];
  #pragma unroll
  for (int mt = 0; mt < 4; ++mt)
    #pragma unroll
    for (int nt = 0; nt < 4; ++nt) acc[mt][nt] = (f32x4)0.f;

  for (int kt = 0; kt < 16; ++kt) {
    const int k0 = kbase + kt*64;
    __syncthreads();
    #pragma unroll
    for (int u = 0; u < 4; ++u) {
      int r = wv*32 + u*8 + sr;
      int c = sp ^ (r & 7);
      gload_lds16(&h4c[(size_t)(M0 + r)*16384 + k0 + c*8], &a_s[(wv*32 + u*8)*64]);
      gload_lds16(&ewt[(size_t)(N0 + r)*16384 + k0 + c*8], &b_s[(wv*32 + u*8)*64]);
    }
    __syncthreads();
    #pragma unroll
    for (int ks = 0; ks < 2; ++ks) {
      bf16x8 af[4], bf[4];
      #pragma unroll
      for (int mt = 0; mt < 4; ++mt) {
        int r = mrow0 + mt*16 + row16;
        int p = (ks*4 + quad) ^ (r & 7);
        af[mt] = *(const bf16x8*)&a_s[r*64 + p*8];
      }
      #pragma unroll
      for (int nt = 0; nt < 4; ++nt) {
        int r = ncol0 + nt*16 + row16;
        int p = (ks*4 + quad) ^ (r & 7);
        bf[nt] = *(const bf16x8*)&b_s[r*64 + p*8];
      }
      #pragma unroll
      for (int mt = 0; mt < 4; ++mt)
        #pragma unroll
        for (int nt = 0; nt < 4; ++nt)
          acc[mt][nt] = __builtin_amdgcn_mfma_f32_16x16x32_bf16(af[mt], bf[nt], acc[mt][nt], 0, 0, 0);
    }
  }
  #pragma unroll
  for (int mt = 0; mt < 4; ++mt) {
    int mrow = M0 + mrow0 + mt*16 + quad*4;
    #pragma unroll
    for (int nt = 0; nt < 4; ++nt) {
      int col = N0 + ncol0 + nt*16 + row16;
      #pragma unroll
      for (int r = 0; r < 4; ++r)
        atomicAdd(&z0[(size_t)(img_base + mrow + r)*256 + col], acc[mt][nt][r]);
    }
  }
}

// ---------------- post v2: fully-fused MFMA tail, 16 img/block, grid 256 ----------
__global__ void __launch_bounds__(256) k_post2(const float* __restrict__ z0,
    const float* __restrict__ enc_b, const float* __restrict__ nfb,
    const ushort* __restrict__ nfwt, const ushort* __restrict__ pjd,
    const ushort* __restrict__ gjd, const ushort* __restrict__ ptb,
    const float* __restrict__ ws, const float* __restrict__ clf_b,
    float* __restrict__ out) {
  __shared__ ushort zin[16*264];   // 8448 B
  __shared__ ushort zS [16*264];   // 8448 B
  __shared__ float  Df [16*264];   // 16896 B (l / blended)
  __shared__ ushort wS [16*264];   // 8448 B
  __shared__ float  z2s[16];
  const int t = threadIdx.x, bx = blockIdx.x;
  const int img0 = bx*16;
  #pragma unroll
  for (int u = 0; u < 16; ++u) {
    int i = t + u*256;
    int im = i >> 8, d = i & 255;
    zin[im*264 + d] = f2bf(z0[(size_t)(img0 + im)*256 + d] + enc_b[d]);
  }
  __syncthreads();

  const int lane = t & 63, w = t >> 6;
  const int quad = lane >> 4, row16 = lane & 15;
  const int n0 = w*64;

  // ---- phase 1: z = zin @ nfw^T + nfb ----
  f32x4 zC[4];
  #pragma unroll
  for (int nt = 0; nt < 4; ++nt) zC[nt] = (f32x4)0.f;
  #pragma unroll
  for (int ks = 0; ks < 8; ++ks) {
    bf16x8 az = *(const bf16x8*)&zin[row16*264 + ks*32 + quad*8];
    #pragma unroll
    for (int nt = 0; nt < 4; ++nt) {
      bf16x8 bw = *(const bf16x8*)&nfwt[(n0 + nt*16 + row16)*256 + ks*32 + quad*8];
      zC[nt] = __builtin_amdgcn_mfma_f32_16x16x32_bf16(az, bw, zC[nt], 0, 0, 0);
    }
  }
  #pragma unroll
  for (int nt = 0; nt < 4; ++nt) {
    int n = n0 + nt*16 + row16;
    float nb = nfb[n];
    #pragma unroll
    for (int r = 0; r < 4; ++r)
      zS[(quad*4 + r)*264 + n] = f2bf(zC[nt][r] + nb);
  }
  __syncthreads();

  {
    int im = t >> 4, jg = t & 15;
    float s = 0.f;
    #pragma unroll
    for (int q = 0; q < 16; ++q) {
      float v = bf2f(zS[im*264 + jg + 16*q]);
      s += v*v;
    }
    #pragma unroll
    for (int off = 8; off; off >>= 1) s += __shfl_xor(s, off, 16);
    if (jg == 0) z2s[im] = s;
  }
  __syncthreads();

  // ---- phase 2: dp/dg = z @ protos^T / grid^T -> logits l ----
  f32x4 dpC[4], dgC[4];
  #pragma unroll
  for (int nt = 0; nt < 4; ++nt) { dpC[nt] = (f32x4)0.f; dgC[nt] = (f32x4)0.f; }
  #pragma unroll
  for (int ks = 0; ks < 8; ++ks) {
    bf16x8 az = *(const bf16x8*)&zS[row16*264 + ks*32 + quad*8];
    #pragma unroll
    for (int nt = 0; nt < 4; ++nt) {
      int j = n0 + nt*16 + row16;
      bf16x8 bp = *(const bf16x8*)&pjd[j*256 + ks*32 + quad*8];
      bf16x8 bg = *(const bf16x8*)&gjd[j*256 + ks*32 + quad*8];
      dpC[nt] = __builtin_amdgcn_mfma_f32_16x16x32_bf16(az, bp, dpC[nt], 0, 0, 0);
      dgC[nt] = __builtin_amdgcn_mfma_f32_16x16x32_bf16(az, bg, dgC[nt], 0, 0, 0);
    }
  }
  {
    float temp = ws[OFF_TEMP];
    #pragma unroll
    for (int nt = 0; nt < 4; ++nt) {
      int j = n0 + nt*16 + row16;
      float pn = ws[OFF_PN2 + j], gn = ws[OFF_GN2 + j];
      #pragma unroll
      for (int r = 0; r < 4; ++r) {
        int im = quad*4 + r;
        float z2 = z2s[im];
        float d2p = z2 + pn - 2.f*dpC[nt][r];
        float d2g = z2 + gn - 2.f*dgC[nt][r];
        float l = -(sqrtf(fmaxf(d2p, 0.f)) + sqrtf(fmaxf(d2g, 0.f)))/temp;
        Df[im*264 + j] = l;
      }
    }
  }
  __syncthreads();

  // ---- softmax + gate + renorm -> wS bf16 ----
  {
    int im = t >> 4, jg = t & 15;
    float m = -1e30f;
    #pragma unroll
    for (int q = 0; q < 16; ++q) m = fmaxf(m, Df[im*264 + jg + 16*q]);
    #pragma unroll
    for (int off = 8; off; off >>= 1) m = fmaxf(m, __shfl_xor(m, off, 16));
    float E = 0.f, S = 0.f, ev[16], gv[16];
    #pragma unroll
    for (int q = 0; q < 16; ++q) {
      int j = jg + 16*q;
      float e = expf(Df[im*264 + j] - m);
      float g = ws[OFF_GATE + j];
      ev[q] = e; gv[q] = g;
      E += e; S += e*g;
    }
    #pragma unroll
    for (int off = 8; off; off >>= 1) {
      E += __shfl_xor(E, off, 16);
      S += __shfl_xor(S, off, 16);
    }
    float inv = 1.f/(S + 1e-8f*E);
    #pragma unroll
    for (int q = 0; q < 16; ++q)
      wS[im*264 + jg + 16*q] = f2bf(ev[q]*gv[q]*inv);
  }
  __syncthreads();

  // ---- phase 3: blended = w @ protos ----
  f32x4 blC[4];
  #pragma unroll
  for (int nt = 0; nt < 4; ++nt) blC[nt] = (f32x4)0.f;
  #pragma unroll
  for (int ks = 0; ks < 8; ++ks) {
    bf16x8 aw = *(const bf16x8*)&wS[row16*264 + ks*32 + quad*8];
    #pragma unroll
    for (int nt = 0; nt < 4; ++nt) {
      bf16x8 bp = *(const bf16x8*)&ptb[(n0 + nt*16 + row16)*256 + ks*32 + quad*8];
      blC[nt] = __builtin_amdgcn_mfma_f32_16x16x32_bf16(aw, bp, blC[nt], 0, 0, 0);
    }
  }
  #pragma unroll
  for (int nt = 0; nt < 4; ++nt) {
    int d = n0 + nt*16 + row16;
    #pragma unroll
    for (int r = 0; r < 4; ++r)
      Df[(quad*4 + r)*264 + d] = blC[nt][r];
  }
  __syncthreads();

  if (t < 160) {
    int im = t/10, c = t - im*10;
    float s = clf_b[c];
    for (int d = 0; d < 256; ++d)
      s += Df[im*264 + d]*ws[OFF_WEFF + d*10 + c];
    out[(size_t)(img0 + im)*10 + c] = s;
  }
}

extern "C" void kernel_launch(void* const* d_in, const int* in_sizes, int n_in,
                              void* d_out, int out_size, void* d_ws, size_t ws_size,
                              hipStream_t stream) {
  (void)in_sizes; (void)n_in; (void)out_size; (void)ws_size;
  const float* x      = (const float*)d_in[0];
  const float* c1w    = (const float*)d_in[2];
  const float* c1b    = (const float*)d_in[3];
  const float* c2w    = (const float*)d_in[4];
  const float* c2b    = (const float*)d_in[5];
  const float* c3w    = (const float*)d_in[6];
  const float* c3b    = (const float*)d_in[7];
  const float* c4w    = (const float*)d_in[8];
  const float* c4b    = (const float*)d_in[9];
  const float* encw   = (const float*)d_in[10];
  const float* encb   = (const float*)d_in[11];
  // d_in[12..17] dead: softmax over a single node == 1 exactly
  const float* clfw   = (const float*)d_in[18];
  const float* clfb   = (const float*)d_in[19];
  const float* nfw    = (const float*)d_in[20];
  const float* nfb    = (const float*)d_in[21];
  const float* protos = (const float*)d_in[22];
  const float* gridp  = (const float*)d_in[23];
  const float* traw   = (const float*)d_in[24];
  const float* gatel  = (const float*)d_in[25];

  float*  ws   = (float*)d_ws;
  float*  w1t  = ws + OFF_W1T;
  ushort* w2t  = (ushort*)((char*)d_ws + OFF_W2T_BYTES);
  ushort* w3t  = (ushort*)((char*)d_ws + OFF_W3T_BYTES);
  ushort* w4t  = (ushort*)((char*)d_ws + OFF_W4T_BYTES);
  ushort* ewt  = (ushort*)((char*)d_ws + OFF_EWT_BYTES);
  ushort* nfwt = (ushort*)((char*)d_ws + OFF_NFWT_BYTES);
  ushort* pjd  = (ushort*)((char*)d_ws + OFF_PJD_BYTES);
  ushort* gjd  = (ushort*)((char*)d_ws + OFF_GJD_BYTES);
  ushort* ptb  = (ushort*)((char*)d_ws + OFF_PTB_BYTES);
  ushort* h4c  = (ushort*)((char*)d_ws + OFF_A_BYTES);
  ushort* h2c  = (ushort*)((char*)d_ws + OFF_B_BYTES);
  float*  z0   = (float*) ((char*)d_ws + OFF_Z0_BYTES);
  float*  out  = (float*)d_out;

  hipLaunchKernelGGL(k_init, dim3(2688), dim3(TPB), 0, stream,
                     encw, ewt, c1w, c2w, c3w, c4w, w1t, w2t, w3t, w4t,
                     protos, gridp, gatel, traw, clfw, ws, z0,
                     nfw, nfwt, pjd, gjd, ptb);
  hipLaunchKernelGGL(k_conv12, dim3(4096), dim3(TPB), 0, stream, x, w1t, c1b, w2t, c2b, h2c);
  for (int c = 0; c < 2; ++c) {
    hipLaunchKernelGGL(k_conv34, dim3(1024), dim3(TPB), 0, stream,
                       h2c, c3b, c4b, w3t, w4t, h4c, c*2048);
    hipLaunchKernelGGL(k_enc, dim3(512), dim3(TPB), 0, stream, h4c, ewt, z0, c*2048);
  }
  hipLaunchKernelGGL(k_post2, dim3(256), dim3(TPB), 0, stream,
                     z0, encb, nfb, nfwt, pjd, gjd, ptb, ws, clfb, out);
}

// Round 8
// 524.560 us; speedup vs baseline: 1.2594x; 1.2594x over previous
//
#include <hip/hip_runtime.h>
#include <math.h>

#define TPB 256

typedef __attribute__((ext_vector_type(8))) short bf16x8;
typedef __attribute__((ext_vector_type(4))) float f32x4;
typedef __attribute__((ext_vector_type(2))) float f32x2;

// ---------------- workspace layout ----------------
// aux (fp32), float offsets:
#define OFF_PN2   0          // 256
#define OFF_GN2   256        // 256
#define OFF_GATE  512        // 256
#define OFF_TEMP  768        // 1
#define OFF_WEFF  1024       // 2560
#define OFF_W1T   3584       // 2400 fp32: w1t[tap<75][oc<32]
// bf16 weight tables (byte offsets):
#define OFF_W2T_BYTES 737280ul    // 9*64*32   bf16
#define OFF_W3T_BYTES 786432ul    // 9*128*64  bf16
#define OFF_W4T_BYTES 983040ul    // 9*256*128 bf16
#define OFF_EWT_BYTES 2097152ul   // ewt[n=256][k=16384] bf16 = 8 MiB
// post-stage bf16 tables:
#define OFF_NFWT_BYTES 10485760ul // nfwt[n=256][k=256] bf16 = 128 KiB
#define OFF_PJD_BYTES  10616832ul // protos[j][d] bf16
#define OFF_GJD_BYTES  10747904ul // grid[j][d] bf16
#define OFF_PTB_BYTES  10878976ul // protosT[d][j] bf16
// big regions (byte offsets):
#define OFF_A_BYTES   12582912ul  // h4c ping buffer: 2048 img x 32KB = 64 MiB
#define OFF_B_BYTES   (OFF_A_BYTES + 67108864ul)   // h2c: 4096 img x 8KB = 32 MiB
#define OFF_Z0_BYTES  (OFF_B_BYTES + 33554432ul)   // z0: 4096x256 f32 = 4 MiB
// total ~112 MiB

// ---------------- bf16 helpers ----------------
__device__ __forceinline__ float bf2f(ushort u) {
  return __uint_as_float(((unsigned)u) << 16);
}
__device__ __forceinline__ ushort f2bf(float f) {   // RNE
  unsigned x = __float_as_uint(f);
  return (ushort)((x + 0x7fffu + ((x >> 16) & 1u)) >> 16);
}
__device__ __forceinline__ unsigned pack2(float a, float b) {
  return (unsigned)f2bf(a) | ((unsigned)f2bf(b) << 16);
}

// async global->LDS, 16B per lane; lds dest = wave-uniform base + lane*16
__device__ __forceinline__ void gload_lds16(const ushort* g, ushort* l) {
  __builtin_amdgcn_global_load_lds(
      (const __attribute__((address_space(1))) unsigned int*)g,
      (__attribute__((address_space(3))) unsigned int*)l, 16, 0, 0);
}

// ---------------- block reductions ----------------
__device__ __forceinline__ float block_sum(float v, float* red) {
  #pragma unroll
  for (int off = 32; off > 0; off >>= 1) v += __shfl_down(v, off, 64);
  int wid = threadIdx.x >> 6;
  __syncthreads();
  if ((threadIdx.x & 63) == 0) red[wid] = v;
  __syncthreads();
  return red[0] + red[1] + red[2] + red[3];
}

// ---------------- k_init: merged setup + prep + prep2 + trans ------------------
// blocks [0,1024):    trans  (enc_w -> ewt bf16 transpose)
// blocks [1024,2176): prep   (conv weight tables)
// blocks [2176,2432): setup  (norms, gate, temp, weff, z0 zero)
// blocks [2432,2688): prep2  (post-stage bf16 tables)
__global__ void __launch_bounds__(256) k_init(
    const float* __restrict__ ew,    ushort* __restrict__ ewt,
    const float* __restrict__ w1,    const float* __restrict__ w2,
    const float* __restrict__ w3,    const float* __restrict__ w4,
    float* __restrict__ w1t, ushort* __restrict__ w2t,
    ushort* __restrict__ w3t, ushort* __restrict__ w4t,
    const float* __restrict__ protos, const float* __restrict__ gridp,
    const float* __restrict__ gate_logits, const float* __restrict__ temp_raw,
    const float* __restrict__ clf_w, float* __restrict__ ws,
    float* __restrict__ z0,
    const float* __restrict__ nfw, ushort* __restrict__ nfwt,
    ushort* __restrict__ pjd, ushort* __restrict__ gjd,
    ushort* __restrict__ ptb) {
  __shared__ float tile[64][65];
  __shared__ float red[4];
  const int bx = blockIdx.x, t = threadIdx.x;

  if (bx < 1024) {                 // ---- trans ----
    int kb = bx & 255, nb = bx >> 8;
    #pragma unroll
    for (int i = 0; i < 16; ++i) {
      int idx = t + i*256, k = idx >> 6, n = idx & 63;
      tile[k][n] = ew[(size_t)(kb*64 + k)*256 + nb*64 + n];
    }
    __syncthreads();
    #pragma unroll
    for (int i = 0; i < 16; ++i) {
      int idx = t + i*256, n = idx >> 6, k = idx & 63;
      ewt[(size_t)(nb*64 + n)*16384 + kb*64 + k] = f2bf(tile[k][n]);
    }
    return;
  }
  if (bx < 2176) {                 // ---- prep ----
    int idx = (bx - 1024)*256 + t;
    if (idx < 2400) {
      int tap = idx >> 5, oc = idx & 31;
      w1t[idx] = w1[oc*75 + tap];
    }
    if (idx < 18432) {
      int tap = idx >> 11, r = idx & 2047, oc = r >> 5, ic = r & 31;
      w2t[idx] = f2bf(w2[oc*288 + ic*9 + tap]);
    }
    if (idx < 73728) {
      int tap = idx >> 13, r = idx & 8191, oc = r >> 6, ic = r & 63;
      w3t[idx] = f2bf(w3[oc*576 + ic*9 + tap]);
    }
    if (idx < 294912) {
      int tap = idx >> 15, r = idx & 32767, oc = r >> 7, ic = r & 127;
      w4t[idx] = f2bf(w4[oc*1152 + ic*9 + tap]);
    }
    return;
  }
  if (bx < 2432) {                 // ---- setup ----
    int b = bx - 2176;
    #pragma unroll
    for (int u = 0; u < 16; ++u) z0[(size_t)u*65536 + b*256 + t] = 0.f;
    float pv = protos[b*256 + t];
    float gv = gridp [b*256 + t];
    float sp = block_sum(pv*pv, red);
    float sg = block_sum(gv*gv, red);
    if (t == 0) {
      ws[OFF_PN2 + b] = sp;
      ws[OFF_GN2 + b] = sg;
      ws[OFF_GATE + b] = 1.f/(1.f + expf(-gate_logits[b]));
    }
    if (b == 0) {
      for (int i = t; i < 2560; i += TPB) {
        int d = i/10, c = i%10;
        ws[OFF_WEFF + i] = clf_w[d*10+c] + clf_w[(256+d)*10+c]
                         + clf_w[(512+d)*10+c] + clf_w[(768+d)*10+c];
      }
      if (t == 0) {
        float s = 1.f/(1.f + expf(-temp_raw[0]));
        ws[OFF_TEMP] = s*(1.f - 0.001f) + 0.001f;
      }
    }
    return;
  }
  {                                // ---- prep2 ----
    int idx = (bx - 2432)*256 + t;   // 65536
    int a = idx >> 8, b = idx & 255;
    nfwt[idx] = f2bf(nfw[b*256 + a]);     // [n][k] = nfw[k][n]
    pjd [idx] = f2bf(protos[idx]);        // [j][d]
    gjd [idx] = f2bf(gridp[idx]);         // [j][d]
    ptb [idx] = f2bf(protos[b*256 + a]);  // [d][j] = protos[j][d]
  }
}

// ---------------- conv1+conv2 fused v4: minimal LDS (xs only, 23.1 KB) ----------
__global__ void __launch_bounds__(256) k_conv12(const float* __restrict__ x,
    const float* __restrict__ w1t, const float* __restrict__ b1,
    const ushort* __restrict__ w2t, const float* __restrict__ b2,
    ushort* __restrict__ h2c) {
  __shared__ ushort xs[17*17*40];   // 23120 B only
  int b = blockIdx.x, t = threadIdx.x;
  for (int i = t; i < 5780; i += TPB) ((unsigned*)xs)[i] = 0u;
  const float* xb = x + (size_t)b*3072;

  if (t < 225) {               // conv1: one px per thread, all 32 oc, packed f32
    int oy = t/15, ox = t%15;
    f32x2 acc[16];
    #pragma unroll
    for (int o = 0; o < 16; ++o) acc[o] = *(const f32x2*)&b1[2*o];
    for (int ic = 0; ic < 3; ++ic) {
      const int icb = ic*1024;
      #pragma unroll
      for (int ky = 0; ky < 5; ++ky) {
        int iy = 2*oy - 1 + ky;
        bool rok = (unsigned)iy < 32u;
        int rbase = icb + (rok ? iy*32 : 0);
        #pragma unroll
        for (int kx = 0; kx < 5; ++kx) {
          int ix = 2*ox - 1 + kx;
          bool ok = rok && ((unsigned)ix < 32u);
          float xv = xb[rbase + (ok ? ix : 0)];
          xv = ok ? xv : 0.f;
          f32x2 xv2 = {xv, xv};
          const float* wrow = &w1t[(ic*25 + ky*5 + kx)*32];   // wave-uniform -> s_load
          #pragma unroll
          for (int g = 0; g < 8; ++g) {
            f32x2 wlo = {wrow[4*g+0], wrow[4*g+1]};
            f32x2 whi = {wrow[4*g+2], wrow[4*g+3]};
            acc[2*g]   += xv2*wlo;
            acc[2*g+1] += xv2*whi;
          }
        }
      }
    }
    unsigned pk[16];
    #pragma unroll
    for (int g = 0; g < 16; ++g)
      pk[g] = pack2(fmaxf(acc[g].x, 0.f), fmaxf(acc[g].y, 0.f));
    ushort* cell = &xs[((oy+1)*17 + (ox+1))*40];
    #pragma unroll
    for (int q = 0; q < 4; ++q) *(uint4*)(cell + q*8) = ((uint4*)pk)[q];
  }
  __syncthreads();

  // conv2 MFMA (swapped: oc-in-regs): wave w -> oc [w*16, w*16+16)
  const int lane = t & 63, w = t >> 6;
  const int quad = lane >> 4, row16 = lane & 15;
  f32x4 acc2[4];
  #pragma unroll
  for (int mt = 0; mt < 4; ++mt) acc2[mt] = (f32x4)0.f;
  #pragma unroll
  for (int ky = 0; ky < 3; ++ky)
    #pragma unroll
    for (int kx = 0; kx < 3; ++kx) {
      int tap = ky*3 + kx;
      bf16x8 bf = *(const bf16x8*)&w2t[tap*2048 + (w*16 + row16)*32 + quad*8];
      #pragma unroll
      for (int mt = 0; mt < 4; ++mt) {
        int px = mt*16 + row16;
        int iy = 2*(px >> 3) + ky, ix = 2*(px & 7) + kx;
        bf16x8 af = *(const bf16x8*)&xs[(iy*17 + ix)*40 + quad*8];
        acc2[mt] = __builtin_amdgcn_mfma_f32_16x16x32_bf16(bf, af, acc2[mt], 0, 0, 0);
      }
    }
  float4 bb = *(const float4*)&b2[w*16 + quad*4];
  #pragma unroll
  for (int mt = 0; mt < 4; ++mt) {
    int px = mt*16 + row16;
    uint2 dd;
    dd.x = pack2(fmaxf(acc2[mt][0] + bb.x, 0.f), fmaxf(acc2[mt][1] + bb.y, 0.f));
    dd.y = pack2(fmaxf(acc2[mt][2] + bb.z, 0.f), fmaxf(acc2[mt][3] + bb.w, 0.f));
    *(uint2*)&h2c[(size_t)b*4096 + px*64 + w*16 + quad*4] = dd;
  }
}

// ---------------- conv3+conv4 fused v12 (PROVEN 117us): v9 structure + ping fix.
// 256 thr, 4 waves, 2 img/block, launch_bounds(256,2) -> 256-reg budget
// (124 arch + 128 acc, NO spill), halo-in-LDS (10x10 rows, zeroed ring,
// strides 72/136), depth-1 weight prefetch with 16/32 MFMA per step.
// conv4 writes h4c PING rows [0,2048): ig = bl*2 + img.
__global__ void __launch_bounds__(256, 2) k_conv34(const ushort* __restrict__ h2c,
    const float* __restrict__ b3, const float* __restrict__ b4,
    const ushort* __restrict__ w3t, const ushort* __restrict__ w4t,
    ushort* __restrict__ h4c, int img_base) {
  // xp  = [img<2][row<100][72]   (14400 ushorts, 28.8 KB)  -- conv3 input
  // h3p = [img<2][row<100][136]  (27200 ushorts, 54.4 KB)  -- aliased, conv4 input
  __shared__ __attribute__((aligned(16))) ushort buf[27200];
  ushort* xp  = buf;
  ushort* h3p = buf;
  const int bl = blockIdx.x, t = threadIdx.x;

  // ---- zero xp halo ring: 2 img x 36 rows x 9 uint4 ----
  for (int i = t; i < 648; i += 256) {
    int img = (i >= 324), r = i - img*324;
    int row = r/9, c = r - row*9;
    int rr = (row < 20) ? ((row < 10) ? row : row + 80)
                        : (((row-20) >> 1) + 1)*10 + ((row-20) & 1)*9;
    *(uint4*)&xp[img*7200 + rr*72 + c*8] = (uint4){0,0,0,0};
  }
  // ---- stage conv3 input interior (disjoint from ring; no barrier needed) ----
  #pragma unroll
  for (int u = 0; u < 4; ++u) {
    int i = t + u*256;
    int img = i >> 9, px = (i >> 3) & 63, icg = i & 7;
    bf16x8 v = *(const bf16x8*)&h2c[(size_t)(img_base + bl*2 + img)*4096 + px*64 + icg*8];
    int row = ((px >> 3) + 1)*10 + (px & 7) + 1;
    *(bf16x8*)&xp[img*7200 + row*72 + icg*8] = v;
  }
  __syncthreads();

  const int lane = t & 63, w = t >> 6;
  const int quad = lane >> 4, row16 = lane & 15;

  // per-mt LDS base offsets (ushort units); mt = img*4 + px-group
  int b3off[8], b4off[8], r11c[8];
  #pragma unroll
  for (int mt = 0; mt < 8; ++mt) {
    int px = (mt & 3)*16 + row16;
    int r00 = (px >> 3)*10 + (px & 7);     // halo-corner row for tap (0,0)
    int img = mt >> 2;
    b3off[mt] = img*7200  + r00*72  + quad*8;
    b4off[mt] = img*13600 + r00*136 + quad*8;
    r11c[mt]  = img*13600 + (r00 + 11)*136;   // interior row for epilogue
  }

  // ---- conv3: wave = 32 oc (w*32, 2 frags) x 8 mt (2 img x 64 px) ----
  const int ocb3 = w*32;
  f32x4 c3[8][2];
  #pragma unroll
  for (int mt = 0; mt < 8; ++mt) { c3[mt][0] = (f32x4)0.f; c3[mt][1] = (f32x4)0.f; }
  const ushort* w3b = w3t + (ocb3 + row16)*64 + quad*8;
  bf16x8 wa0 = *(const bf16x8*)(w3b);          // (tap0, ks0), oc-lo 16
  bf16x8 wa1 = *(const bf16x8*)(w3b + 1024);   // oc-hi 16
  #pragma unroll
  for (int tap = 0; tap < 9; ++tap) {
    const int t72 = ((tap/3)*10 + (tap%3))*72;     // compile-time after unroll
    #pragma unroll
    for (int ks = 0; ks < 2; ++ks) {
      // depth-1 weight prefetch; tap==8 overshoot reads workspace gap (discarded)
      const ushort* wn = w3b + ((ks == 0) ? (tap*8192 + 32) : ((tap+1)*8192));
      bf16x8 n0 = *(const bf16x8*)(wn);
      bf16x8 n1 = *(const bf16x8*)(wn + 1024);
      #pragma unroll
      for (int mt = 0; mt < 8; ++mt) {
        bf16x8 af = *(const bf16x8*)&xp[b3off[mt] + t72 + ks*32];
        c3[mt][0] = __builtin_amdgcn_mfma_f32_16x16x32_bf16(wa0, af, c3[mt][0], 0, 0, 0);
        c3[mt][1] = __builtin_amdgcn_mfma_f32_16x16x32_bf16(wa1, af, c3[mt][1], 0, 0, 0);
      }
      wa0 = n0; wa1 = n1;
    }
  }
  __syncthreads();   // ALIAS BARRIER: all xp reads done before h3p overwrites buf

  // ---- zero h3p halo ring: 2 img x 36 rows x 17 uint4 (disjoint from interior) ----
  for (int i = t; i < 1224; i += 256) {
    int img2 = (i >= 612), r = i - img2*612;
    int row = r/17, c = r - row*17;
    int rr = (row < 20) ? ((row < 10) ? row : row + 80)
                        : (((row-20) >> 1) + 1)*10 + ((row-20) & 1)*9;
    *(uint4*)&h3p[img2*13600 + rr*136 + c*8] = (uint4){0,0,0,0};
  }
  // ---- conv3 epilogue: D col=px(row16), row=oc(quad*4+r) -> h3p interior ----
  #pragma unroll
  for (int nt = 0; nt < 2; ++nt) {
    float4 bb = *(const float4*)&b3[ocb3 + nt*16 + quad*4];
    #pragma unroll
    for (int mt = 0; mt < 8; ++mt) {
      uint2 dd;
      dd.x = pack2(fmaxf(c3[mt][nt][0] + bb.x, 0.f), fmaxf(c3[mt][nt][1] + bb.y, 0.f));
      dd.y = pack2(fmaxf(c3[mt][nt][2] + bb.z, 0.f), fmaxf(c3[mt][nt][3] + bb.w, 0.f));
      *(uint2*)&h3p[r11c[mt] + ocb3 + nt*16 + quad*4] = dd;
    }
  }
  __syncthreads();

  // ---- conv4: wave = 64 oc (w*64, 4 frags) x 8 mt (2 img x 64 px) ----
  const int ocb4 = w*64;
  f32x4 c4[8][4];
  #pragma unroll
  for (int mt = 0; mt < 8; ++mt)
    #pragma unroll
    for (int nt = 0; nt < 4; ++nt) c4[mt][nt] = (f32x4)0.f;
  const ushort* w4b = w4t + (ocb4 + row16)*128 + quad*8;
  bf16x8 r4[4];
  #pragma unroll
  for (int nt = 0; nt < 4; ++nt) r4[nt] = *(const bf16x8*)(w4b + nt*2048);
  #pragma unroll
  for (int tap = 0; tap < 9; ++tap) {
    const int t136 = ((tap/3)*10 + (tap%3))*136;
    #pragma unroll
    for (int ks = 0; ks < 4; ++ks) {
      // depth-1 prefetch of next step's 4 weight frags; tap==8 overshoot in gap
      const ushort* wn = w4b + ((ks < 3) ? (tap*32768 + (ks+1)*32) : ((tap+1)*32768));
      bf16x8 nx[4];
      #pragma unroll
      for (int nt = 0; nt < 4; ++nt) nx[nt] = *(const bf16x8*)(wn + nt*2048);
      #pragma unroll
      for (int mt = 0; mt < 8; ++mt) {
        bf16x8 ax = *(const bf16x8*)&h3p[b4off[mt] + t136 + ks*32];
        #pragma unroll
        for (int nt = 0; nt < 4; ++nt)
          c4[mt][nt] = __builtin_amdgcn_mfma_f32_16x16x32_bf16(ax, r4[nt], c4[mt][nt], 0, 0, 0);
      }
      #pragma unroll
      for (int nt = 0; nt < 4; ++nt) r4[nt] = nx[nt];
    }
  }
  // ---- conv4 epilogue: D col=oc(row16), row=px(quad*4+r) -> h4c PING rows ----
  #pragma unroll
  for (int nt = 0; nt < 4; ++nt) {
    int oc = ocb4 + nt*16 + row16;
    float bv = b4[oc];
    #pragma unroll
    for (int mt = 0; mt < 8; ++mt) {
      int ig = bl*2 + (mt >> 2);             // ping-buffer row [0,2048)
      int px0 = (mt & 3)*16 + quad*4;
      uint2 dd;
      dd.x = pack2(fmaxf(c4[mt][nt][0] + bv, 0.f), fmaxf(c4[mt][nt][1] + bv, 0.f));
      dd.y = pack2(fmaxf(c4[mt][nt][2] + bv, 0.f), fmaxf(c4[mt][nt][3] + bv, 0.f));
      *(uint2*)&h4c[(size_t)ig*16384 + oc*64 + px0] = dd;
    }
  }
}

// ---------------- enc: z0 += h4c @ ewt^T, MFMA bf16, split-K=16, 128x128 tiles ------
__global__ void __launch_bounds__(256) k_enc(const ushort* __restrict__ h4c,
    const ushort* __restrict__ ewt, float* __restrict__ z0, int img_base) {
  __shared__ ushort a_s[128*64];   // 16 KB
  __shared__ ushort b_s[128*64];   // 16 KB
  const int t = threadIdx.x, bx = blockIdx.x;
  const int slice = bx & 15;
  const int mb = (bx >> 4) & 15;
  const int nb = bx >> 8;
  const int M0 = mb*128, N0 = nb*128;
  const int kbase = slice*1024;
  const int lane = t & 63, wv = t >> 6;
  const int quad = lane >> 4, row16 = lane & 15;
  const int mrow0 = (wv & 1)*64, ncol0 = (wv >> 1)*64;
  const int sr = lane >> 3, sp = lane & 7;

  f32x4 acc[4][4];
  #pragma unroll
  for (int mt = 0; mt < 4; ++mt)
    #pragma unroll
    for (int nt = 0; nt < 4; ++nt) acc[mt][nt] = (f32x4)0.f;

  for (int kt = 0; kt < 16; ++kt) {
    const int k0 = kbase + kt*64;
    __syncthreads();
    #pragma unroll
    for (int u = 0; u < 4; ++u) {
      int r = wv*32 + u*8 + sr;
      int c = sp ^ (r & 7);
      gload_lds16(&h4c[(size_t)(M0 + r)*16384 + k0 + c*8], &a_s[(wv*32 + u*8)*64]);
      gload_lds16(&ewt[(size_t)(N0 + r)*16384 + k0 + c*8], &b_s[(wv*32 + u*8)*64]);
    }
    __syncthreads();
    #pragma unroll
    for (int ks = 0; ks < 2; ++ks) {
      bf16x8 af[4], bf[4];
      #pragma unroll
      for (int mt = 0; mt < 4; ++mt) {
        int r = mrow0 + mt*16 + row16;
        int p = (ks*4 + quad) ^ (r & 7);
        af[mt] = *(const bf16x8*)&a_s[r*64 + p*8];
      }
      #pragma unroll
      for (int nt = 0; nt < 4; ++nt) {
        int r = ncol0 + nt*16 + row16;
        int p = (ks*4 + quad) ^ (r & 7);
        bf[nt] = *(const bf16x8*)&b_s[r*64 + p*8];
      }
      #pragma unroll
      for (int mt = 0; mt < 4; ++mt)
        #pragma unroll
        for (int nt = 0; nt < 4; ++nt)
          acc[mt][nt] = __builtin_amdgcn_mfma_f32_16x16x32_bf16(af[mt], bf[nt], acc[mt][nt], 0, 0, 0);
    }
  }
  #pragma unroll
  for (int mt = 0; mt < 4; ++mt) {
    int mrow = M0 + mrow0 + mt*16 + quad*4;
    #pragma unroll
    for (int nt = 0; nt < 4; ++nt) {
      int col = N0 + ncol0 + nt*16 + row16;
      #pragma unroll
      for (int r = 0; r < 4; ++r)
        atomicAdd(&z0[(size_t)(img_base + mrow + r)*256 + col], acc[mt][nt][r]);
    }
  }
}

// ---------------- post v3: fully-fused MFMA tail, 16 img/block, grid 256;
// weff (2560 f32) staged to LDS — v2's tail did 256 stride-10 GLOBAL scalar
// loads per thread at 1 blk/CU (serial latency chain); now LDS reads. ----------
__global__ void __launch_bounds__(256) k_post2(const float* __restrict__ z0,
    const float* __restrict__ enc_b, const float* __restrict__ nfb,
    const ushort* __restrict__ nfwt, const ushort* __restrict__ pjd,
    const ushort* __restrict__ gjd, const ushort* __restrict__ ptb,
    const float* __restrict__ ws, const float* __restrict__ clf_b,
    float* __restrict__ out) {
  __shared__ ushort zin[16*264];   // 8448 B
  __shared__ ushort zS [16*264];   // 8448 B
  __shared__ float  Df [16*264];   // 16896 B (l / blended)
  __shared__ ushort wS [16*264];   // 8448 B
  __shared__ float  weffS[2560];   // 10240 B
  __shared__ float  z2s[16];
  const int t = threadIdx.x, bx = blockIdx.x;
  const int img0 = bx*16;
  #pragma unroll
  for (int u = 0; u < 10; ++u)
    weffS[t + u*256] = ws[OFF_WEFF + t + u*256];
  #pragma unroll
  for (int u = 0; u < 16; ++u) {
    int i = t + u*256;
    int im = i >> 8, d = i & 255;
    zin[im*264 + d] = f2bf(z0[(size_t)(img0 + im)*256 + d] + enc_b[d]);
  }
  __syncthreads();

  const int lane = t & 63, w = t >> 6;
  const int quad = lane >> 4, row16 = lane & 15;
  const int n0 = w*64;

  // ---- phase 1: z = zin @ nfw^T + nfb ----
  f32x4 zC[4];
  #pragma unroll
  for (int nt = 0; nt < 4; ++nt) zC[nt] = (f32x4)0.f;
  #pragma unroll
  for (int ks = 0; ks < 8; ++ks) {
    bf16x8 az = *(const bf16x8*)&zin[row16*264 + ks*32 + quad*8];
    #pragma unroll
    for (int nt = 0; nt < 4; ++nt) {
      bf16x8 bw = *(const bf16x8*)&nfwt[(n0 + nt*16 + row16)*256 + ks*32 + quad*8];
      zC[nt] = __builtin_amdgcn_mfma_f32_16x16x32_bf16(az, bw, zC[nt], 0, 0, 0);
    }
  }
  #pragma unroll
  for (int nt = 0; nt < 4; ++nt) {
    int n = n0 + nt*16 + row16;
    float nb = nfb[n];
    #pragma unroll
    for (int r = 0; r < 4; ++r)
      zS[(quad*4 + r)*264 + n] = f2bf(zC[nt][r] + nb);
  }
  __syncthreads();

  {
    int im = t >> 4, jg = t & 15;
    float s = 0.f;
    #pragma unroll
    for (int q = 0; q < 16; ++q) {
      float v = bf2f(zS[im*264 + jg + 16*q]);
      s += v*v;
    }
    #pragma unroll
    for (int off = 8; off; off >>= 1) s += __shfl_xor(s, off, 16);
    if (jg == 0) z2s[im] = s;
  }
  __syncthreads();

  // ---- phase 2: dp/dg = z @ protos^T / grid^T -> logits l ----
  f32x4 dpC[4], dgC[4];
  #pragma unroll
  for (int nt = 0; nt < 4; ++nt) { dpC[nt] = (f32x4)0.f; dgC[nt] = (f32x4)0.f; }
  #pragma unroll
  for (int ks = 0; ks < 8; ++ks) {
    bf16x8 az = *(const bf16x8*)&zS[row16*264 + ks*32 + quad*8];
    #pragma unroll
    for (int nt = 0; nt < 4; ++nt) {
      int j = n0 + nt*16 + row16;
      bf16x8 bp = *(const bf16x8*)&pjd[j*256 + ks*32 + quad*8];
      bf16x8 bg = *(const bf16x8*)&gjd[j*256 + ks*32 + quad*8];
      dpC[nt] = __builtin_amdgcn_mfma_f32_16x16x32_bf16(az, bp, dpC[nt], 0, 0, 0);
      dgC[nt] = __builtin_amdgcn_mfma_f32_16x16x32_bf16(az, bg, dgC[nt], 0, 0, 0);
    }
  }
  {
    float temp = ws[OFF_TEMP];
    #pragma unroll
    for (int nt = 0; nt < 4; ++nt) {
      int j = n0 + nt*16 + row16;
      float pn = ws[OFF_PN2 + j], gn = ws[OFF_GN2 + j];
      #pragma unroll
      for (int r = 0; r < 4; ++r) {
        int im = quad*4 + r;
        float z2 = z2s[im];
        float d2p = z2 + pn - 2.f*dpC[nt][r];
        float d2g = z2 + gn - 2.f*dgC[nt][r];
        float l = -(sqrtf(fmaxf(d2p, 0.f)) + sqrtf(fmaxf(d2g, 0.f)))/temp;
        Df[im*264 + j] = l;
      }
    }
  }
  __syncthreads();

  // ---- softmax + gate + renorm -> wS bf16 ----
  {
    int im = t >> 4, jg = t & 15;
    float m = -1e30f;
    #pragma unroll
    for (int q = 0; q < 16; ++q) m = fmaxf(m, Df[im*264 + jg + 16*q]);
    #pragma unroll
    for (int off = 8; off; off >>= 1) m = fmaxf(m, __shfl_xor(m, off, 16));
    float E = 0.f, S = 0.f, ev[16], gv[16];
    #pragma unroll
    for (int q = 0; q < 16; ++q) {
      int j = jg + 16*q;
      float e = expf(Df[im*264 + j] - m);
      float g = ws[OFF_GATE + j];
      ev[q] = e; gv[q] = g;
      E += e; S += e*g;
    }
    #pragma unroll
    for (int off = 8; off; off >>= 1) {
      E += __shfl_xor(E, off, 16);
      S += __shfl_xor(S, off, 16);
    }
    float inv = 1.f/(S + 1e-8f*E);
    #pragma unroll
    for (int q = 0; q < 16; ++q)
      wS[im*264 + jg + 16*q] = f2bf(ev[q]*gv[q]*inv);
  }
  __syncthreads();

  // ---- phase 3: blended = w @ protos ----
  f32x4 blC[4];
  #pragma unroll
  for (int nt = 0; nt < 4; ++nt) blC[nt] = (f32x4)0.f;
  #pragma unroll
  for (int ks = 0; ks < 8; ++ks) {
    bf16x8 aw = *(const bf16x8*)&wS[row16*264 + ks*32 + quad*8];
    #pragma unroll
    for (int nt = 0; nt < 4; ++nt) {
      bf16x8 bp = *(const bf16x8*)&ptb[(n0 + nt*16 + row16)*256 + ks*32 + quad*8];
      blC[nt] = __builtin_amdgcn_mfma_f32_16x16x32_bf16(aw, bp, blC[nt], 0, 0, 0);
    }
  }
  #pragma unroll
  for (int nt = 0; nt < 4; ++nt) {
    int d = n0 + nt*16 + row16;
    #pragma unroll
    for (int r = 0; r < 4; ++r)
      Df[(quad*4 + r)*264 + d] = blC[nt][r];
  }
  __syncthreads();

  if (t < 160) {
    int im = t/10, c = t - im*10;
    float s = clf_b[c];
    for (int d = 0; d < 256; ++d)
      s += Df[im*264 + d]*weffS[d*10 + c];
    out[(size_t)(img0 + im)*10 + c] = s;
  }
}

extern "C" void kernel_launch(void* const* d_in, const int* in_sizes, int n_in,
                              void* d_out, int out_size, void* d_ws, size_t ws_size,
                              hipStream_t stream) {
  (void)in_sizes; (void)n_in; (void)out_size; (void)ws_size;
  const float* x      = (const float*)d_in[0];
  const float* c1w    = (const float*)d_in[2];
  const float* c1b    = (const float*)d_in[3];
  const float* c2w    = (const float*)d_in[4];
  const float* c2b    = (const float*)d_in[5];
  const float* c3w    = (const float*)d_in[6];
  const float* c3b    = (const float*)d_in[7];
  const float* c4w    = (const float*)d_in[8];
  const float* c4b    = (const float*)d_in[9];
  const float* encw   = (const float*)d_in[10];
  const float* encb   = (const float*)d_in[11];
  // d_in[12..17] dead: softmax over a single node == 1 exactly
  const float* clfw   = (const float*)d_in[18];
  const float* clfb   = (const float*)d_in[19];
  const float* nfw    = (const float*)d_in[20];
  const float* nfb    = (const float*)d_in[21];
  const float* protos = (const float*)d_in[22];
  const float* gridp  = (const float*)d_in[23];
  const float* traw   = (const float*)d_in[24];
  const float* gatel  = (const float*)d_in[25];

  float*  ws   = (float*)d_ws;
  float*  w1t  = ws + OFF_W1T;
  ushort* w2t  = (ushort*)((char*)d_ws + OFF_W2T_BYTES);
  ushort* w3t  = (ushort*)((char*)d_ws + OFF_W3T_BYTES);
  ushort* w4t  = (ushort*)((char*)d_ws + OFF_W4T_BYTES);
  ushort* ewt  = (ushort*)((char*)d_ws + OFF_EWT_BYTES);
  ushort* nfwt = (ushort*)((char*)d_ws + OFF_NFWT_BYTES);
  ushort* pjd  = (ushort*)((char*)d_ws + OFF_PJD_BYTES);
  ushort* gjd  = (ushort*)((char*)d_ws + OFF_GJD_BYTES);
  ushort* ptb  = (ushort*)((char*)d_ws + OFF_PTB_BYTES);
  ushort* h4c  = (ushort*)((char*)d_ws + OFF_A_BYTES);
  ushort* h2c  = (ushort*)((char*)d_ws + OFF_B_BYTES);
  float*  z0   = (float*) ((char*)d_ws + OFF_Z0_BYTES);
  float*  out  = (float*)d_out;

  hipLaunchKernelGGL(k_init, dim3(2688), dim3(TPB), 0, stream,
                     encw, ewt, c1w, c2w, c3w, c4w, w1t, w2t, w3t, w4t,
                     protos, gridp, gatel, traw, clfw, ws, z0,
                     nfw, nfwt, pjd, gjd, ptb);
  hipLaunchKernelGGL(k_conv12, dim3(4096), dim3(TPB), 0, stream, x, w1t, c1b, w2t, c2b, h2c);
  for (int c = 0; c < 2; ++c) {
    hipLaunchKernelGGL(k_conv34, dim3(1024), dim3(TPB), 0, stream,
                       h2c, c3b, c4b, w3t, w4t, h4c, c*2048);
    hipLaunchKernelGGL(k_enc, dim3(512), dim3(TPB), 0, stream, h4c, ewt, z0, c*2048);
  }
  hipLaunchKernelGGL(k_post2, dim3(256), dim3(TPB), 0, stream,
                     z0, encb, nfb, nfwt, pjd, gjd, ptb, ws, clfb, out);
}

// Round 9
// 520.144 us; speedup vs baseline: 1.2701x; 1.0085x over previous
//
#include <hip/hip_runtime.h>
#include <math.h>

#define TPB 256

typedef __attribute__((ext_vector_type(8))) short bf16x8;
typedef __attribute__((ext_vector_type(4))) float f32x4;
typedef __attribute__((ext_vector_type(2))) float f32x2;

// ---------------- workspace layout ----------------
// aux (fp32), float offsets:
#define OFF_PN2   0          // 256
#define OFF_GN2   256        // 256
#define OFF_GATE  512        // 256
#define OFF_TEMP  768        // 1
#define OFF_WEFF  1024       // 2560
#define OFF_W1T   3584       // 2400 fp32: w1t[tap<75][oc<32]
// bf16 weight tables (byte offsets):
#define OFF_W2T_BYTES 737280ul    // 9*64*32   bf16
#define OFF_W3T_BYTES 786432ul    // 9*128*64  bf16
#define OFF_W4T_BYTES 983040ul    // 9*256*128 bf16
#define OFF_EWT_BYTES 2097152ul   // ewt[n=256][k=16384] bf16 = 8 MiB
// post-stage bf16 tables:
#define OFF_NFWT_BYTES 10485760ul // nfwt[n=256][k=256] bf16 = 128 KiB
#define OFF_PJD_BYTES  10616832ul // protos[j][d] bf16
#define OFF_GJD_BYTES  10747904ul // grid[j][d] bf16
#define OFF_PTB_BYTES  10878976ul // protosT[d][j] bf16
// big regions (byte offsets):
#define OFF_A_BYTES   12582912ul  // h4c ping buffer: 2048 img x 32KB = 64 MiB
#define OFF_B_BYTES   (OFF_A_BYTES + 67108864ul)   // h2c: 4096 img x 8KB = 32 MiB
#define OFF_Z0_BYTES  (OFF_B_BYTES + 33554432ul)   // z0: 4096x256 f32 = 4 MiB
// total ~112 MiB

// ---------------- bf16 helpers ----------------
__device__ __forceinline__ float bf2f(ushort u) {
  return __uint_as_float(((unsigned)u) << 16);
}
__device__ __forceinline__ ushort f2bf(float f) {   // RNE
  unsigned x = __float_as_uint(f);
  return (ushort)((x + 0x7fffu + ((x >> 16) & 1u)) >> 16);
}
__device__ __forceinline__ unsigned pack2(float a, float b) {
  return (unsigned)f2bf(a) | ((unsigned)f2bf(b) << 16);
}

// async global->LDS, 16B per lane; lds dest = wave-uniform base + lane*16
__device__ __forceinline__ void gload_lds16(const ushort* g, ushort* l) {
  __builtin_amdgcn_global_load_lds(
      (const __attribute__((address_space(1))) unsigned int*)g,
      (__attribute__((address_space(3))) unsigned int*)l, 16, 0, 0);
}

// ---------------- block reductions ----------------
__device__ __forceinline__ float block_sum(float v, float* red) {
  #pragma unroll
  for (int off = 32; off > 0; off >>= 1) v += __shfl_down(v, off, 64);
  int wid = threadIdx.x >> 6;
  __syncthreads();
  if ((threadIdx.x & 63) == 0) red[wid] = v;
  __syncthreads();
  return red[0] + red[1] + red[2] + red[3];
}

// ---------------- k_init: merged setup + prep + prep2 + trans ------------------
// blocks [0,1024):    trans  (enc_w -> ewt bf16 transpose)
// blocks [1024,2176): prep   (conv weight tables)
// blocks [2176,2432): setup  (norms, gate, temp, weff, z0 zero)
// blocks [2432,2688): prep2  (post-stage bf16 tables)
__global__ void __launch_bounds__(256) k_init(
    const float* __restrict__ ew,    ushort* __restrict__ ewt,
    const float* __restrict__ w1,    const float* __restrict__ w2,
    const float* __restrict__ w3,    const float* __restrict__ w4,
    float* __restrict__ w1t, ushort* __restrict__ w2t,
    ushort* __restrict__ w3t, ushort* __restrict__ w4t,
    const float* __restrict__ protos, const float* __restrict__ gridp,
    const float* __restrict__ gate_logits, const float* __restrict__ temp_raw,
    const float* __restrict__ clf_w, float* __restrict__ ws,
    float* __restrict__ z0,
    const float* __restrict__ nfw, ushort* __restrict__ nfwt,
    ushort* __restrict__ pjd, ushort* __restrict__ gjd,
    ushort* __restrict__ ptb) {
  __shared__ float tile[64][65];
  __shared__ float red[4];
  const int bx = blockIdx.x, t = threadIdx.x;

  if (bx < 1024) {                 // ---- trans ----
    int kb = bx & 255, nb = bx >> 8;
    #pragma unroll
    for (int i = 0; i < 16; ++i) {
      int idx = t + i*256, k = idx >> 6, n = idx & 63;
      tile[k][n] = ew[(size_t)(kb*64 + k)*256 + nb*64 + n];
    }
    __syncthreads();
    #pragma unroll
    for (int i = 0; i < 16; ++i) {
      int idx = t + i*256, n = idx >> 6, k = idx & 63;
      ewt[(size_t)(nb*64 + n)*16384 + kb*64 + k] = f2bf(tile[k][n]);
    }
    return;
  }
  if (bx < 2176) {                 // ---- prep ----
    int idx = (bx - 1024)*256 + t;
    if (idx < 2400) {
      int tap = idx >> 5, oc = idx & 31;
      w1t[idx] = w1[oc*75 + tap];
    }
    if (idx < 18432) {
      int tap = idx >> 11, r = idx & 2047, oc = r >> 5, ic = r & 31;
      w2t[idx] = f2bf(w2[oc*288 + ic*9 + tap]);
    }
    if (idx < 73728) {
      int tap = idx >> 13, r = idx & 8191, oc = r >> 6, ic = r & 63;
      w3t[idx] = f2bf(w3[oc*576 + ic*9 + tap]);
    }
    if (idx < 294912) {
      int tap = idx >> 15, r = idx & 32767, oc = r >> 7, ic = r & 127;
      w4t[idx] = f2bf(w4[oc*1152 + ic*9 + tap]);
    }
    return;
  }
  if (bx < 2432) {                 // ---- setup ----
    int b = bx - 2176;
    #pragma unroll
    for (int u = 0; u < 16; ++u) z0[(size_t)u*65536 + b*256 + t] = 0.f;
    float pv = protos[b*256 + t];
    float gv = gridp [b*256 + t];
    float sp = block_sum(pv*pv, red);
    float sg = block_sum(gv*gv, red);
    if (t == 0) {
      ws[OFF_PN2 + b] = sp;
      ws[OFF_GN2 + b] = sg;
      ws[OFF_GATE + b] = 1.f/(1.f + expf(-gate_logits[b]));
    }
    if (b == 0) {
      for (int i = t; i < 2560; i += TPB) {
        int d = i/10, c = i%10;
        ws[OFF_WEFF + i] = clf_w[d*10+c] + clf_w[(256+d)*10+c]
                         + clf_w[(512+d)*10+c] + clf_w[(768+d)*10+c];
      }
      if (t == 0) {
        float s = 1.f/(1.f + expf(-temp_raw[0]));
        ws[OFF_TEMP] = s*(1.f - 0.001f) + 0.001f;
      }
    }
    return;
  }
  {                                // ---- prep2 ----
    int idx = (bx - 2432)*256 + t;   // 65536
    int a = idx >> 8, b = idx & 255;
    nfwt[idx] = f2bf(nfw[b*256 + a]);     // [n][k] = nfw[k][n]
    pjd [idx] = f2bf(protos[idx]);        // [j][d]
    gjd [idx] = f2bf(gridp[idx]);         // [j][d]
    ptb [idx] = f2bf(protos[b*256 + a]);  // [d][j] = protos[j][d]
  }
}

// ---------------- conv1+conv2 fused v4: minimal LDS (xs only, 23.1 KB) ----------
__global__ void __launch_bounds__(256) k_conv12(const float* __restrict__ x,
    const float* __restrict__ w1t, const float* __restrict__ b1,
    const ushort* __restrict__ w2t, const float* __restrict__ b2,
    ushort* __restrict__ h2c) {
  __shared__ ushort xs[17*17*40];   // 23120 B only
  int b = blockIdx.x, t = threadIdx.x;
  for (int i = t; i < 5780; i += TPB) ((unsigned*)xs)[i] = 0u;
  const float* xb = x + (size_t)b*3072;

  if (t < 225) {               // conv1: one px per thread, all 32 oc, packed f32
    int oy = t/15, ox = t%15;
    f32x2 acc[16];
    #pragma unroll
    for (int o = 0; o < 16; ++o) acc[o] = *(const f32x2*)&b1[2*o];
    for (int ic = 0; ic < 3; ++ic) {
      const int icb = ic*1024;
      #pragma unroll
      for (int ky = 0; ky < 5; ++ky) {
        int iy = 2*oy - 1 + ky;
        bool rok = (unsigned)iy < 32u;
        int rbase = icb + (rok ? iy*32 : 0);
        #pragma unroll
        for (int kx = 0; kx < 5; ++kx) {
          int ix = 2*ox - 1 + kx;
          bool ok = rok && ((unsigned)ix < 32u);
          float xv = xb[rbase + (ok ? ix : 0)];
          xv = ok ? xv : 0.f;
          f32x2 xv2 = {xv, xv};
          const float* wrow = &w1t[(ic*25 + ky*5 + kx)*32];   // wave-uniform -> s_load
          #pragma unroll
          for (int g = 0; g < 8; ++g) {
            f32x2 wlo = {wrow[4*g+0], wrow[4*g+1]};
            f32x2 whi = {wrow[4*g+2], wrow[4*g+3]};
            acc[2*g]   += xv2*wlo;
            acc[2*g+1] += xv2*whi;
          }
        }
      }
    }
    unsigned pk[16];
    #pragma unroll
    for (int g = 0; g < 16; ++g)
      pk[g] = pack2(fmaxf(acc[g].x, 0.f), fmaxf(acc[g].y, 0.f));
    ushort* cell = &xs[((oy+1)*17 + (ox+1))*40];
    #pragma unroll
    for (int q = 0; q < 4; ++q) *(uint4*)(cell + q*8) = ((uint4*)pk)[q];
  }
  __syncthreads();

  // conv2 MFMA (swapped: oc-in-regs): wave w -> oc [w*16, w*16+16)
  const int lane = t & 63, w = t >> 6;
  const int quad = lane >> 4, row16 = lane & 15;
  f32x4 acc2[4];
  #pragma unroll
  for (int mt = 0; mt < 4; ++mt) acc2[mt] = (f32x4)0.f;
  #pragma unroll
  for (int ky = 0; ky < 3; ++ky)
    #pragma unroll
    for (int kx = 0; kx < 3; ++kx) {
      int tap = ky*3 + kx;
      bf16x8 bf = *(const bf16x8*)&w2t[tap*2048 + (w*16 + row16)*32 + quad*8];
      #pragma unroll
      for (int mt = 0; mt < 4; ++mt) {
        int px = mt*16 + row16;
        int iy = 2*(px >> 3) + ky, ix = 2*(px & 7) + kx;
        bf16x8 af = *(const bf16x8*)&xs[(iy*17 + ix)*40 + quad*8];
        acc2[mt] = __builtin_amdgcn_mfma_f32_16x16x32_bf16(bf, af, acc2[mt], 0, 0, 0);
      }
    }
  float4 bb = *(const float4*)&b2[w*16 + quad*4];
  #pragma unroll
  for (int mt = 0; mt < 4; ++mt) {
    int px = mt*16 + row16;
    uint2 dd;
    dd.x = pack2(fmaxf(acc2[mt][0] + bb.x, 0.f), fmaxf(acc2[mt][1] + bb.y, 0.f));
    dd.y = pack2(fmaxf(acc2[mt][2] + bb.z, 0.f), fmaxf(acc2[mt][3] + bb.w, 0.f));
    *(uint2*)&h2c[(size_t)b*4096 + px*64 + w*16 + quad*4] = dd;
  }
}

// ---------------- conv3+conv4 fused v12 (PROVEN 115us): v9 structure + ping fix.
// 256 thr, 4 waves, 2 img/block, launch_bounds(256,2) -> 256-reg budget
// (124 arch + 128 acc, NO spill), halo-in-LDS (10x10 rows, zeroed ring,
// strides 72/136), depth-1 weight prefetch with 16/32 MFMA per step.
// conv4 writes h4c PING rows [0,2048): ig = bl*2 + img.
__global__ void __launch_bounds__(256, 2) k_conv34(const ushort* __restrict__ h2c,
    const float* __restrict__ b3, const float* __restrict__ b4,
    const ushort* __restrict__ w3t, const ushort* __restrict__ w4t,
    ushort* __restrict__ h4c, int img_base) {
  // xp  = [img<2][row<100][72]   (14400 ushorts, 28.8 KB)  -- conv3 input
  // h3p = [img<2][row<100][136]  (27200 ushorts, 54.4 KB)  -- aliased, conv4 input
  __shared__ __attribute__((aligned(16))) ushort buf[27200];
  ushort* xp  = buf;
  ushort* h3p = buf;
  const int bl = blockIdx.x, t = threadIdx.x;

  // ---- zero xp halo ring: 2 img x 36 rows x 9 uint4 ----
  for (int i = t; i < 648; i += 256) {
    int img = (i >= 324), r = i - img*324;
    int row = r/9, c = r - row*9;
    int rr = (row < 20) ? ((row < 10) ? row : row + 80)
                        : (((row-20) >> 1) + 1)*10 + ((row-20) & 1)*9;
    *(uint4*)&xp[img*7200 + rr*72 + c*8] = (uint4){0,0,0,0};
  }
  // ---- stage conv3 input interior (disjoint from ring; no barrier needed) ----
  #pragma unroll
  for (int u = 0; u < 4; ++u) {
    int i = t + u*256;
    int img = i >> 9, px = (i >> 3) & 63, icg = i & 7;
    bf16x8 v = *(const bf16x8*)&h2c[(size_t)(img_base + bl*2 + img)*4096 + px*64 + icg*8];
    int row = ((px >> 3) + 1)*10 + (px & 7) + 1;
    *(bf16x8*)&xp[img*7200 + row*72 + icg*8] = v;
  }
  __syncthreads();

  const int lane = t & 63, w = t >> 6;
  const int quad = lane >> 4, row16 = lane & 15;

  // per-mt LDS base offsets (ushort units); mt = img*4 + px-group
  int b3off[8], b4off[8], r11c[8];
  #pragma unroll
  for (int mt = 0; mt < 8; ++mt) {
    int px = (mt & 3)*16 + row16;
    int r00 = (px >> 3)*10 + (px & 7);     // halo-corner row for tap (0,0)
    int img = mt >> 2;
    b3off[mt] = img*7200  + r00*72  + quad*8;
    b4off[mt] = img*13600 + r00*136 + quad*8;
    r11c[mt]  = img*13600 + (r00 + 11)*136;   // interior row for epilogue
  }

  // ---- conv3: wave = 32 oc (w*32, 2 frags) x 8 mt (2 img x 64 px) ----
  const int ocb3 = w*32;
  f32x4 c3[8][2];
  #pragma unroll
  for (int mt = 0; mt < 8; ++mt) { c3[mt][0] = (f32x4)0.f; c3[mt][1] = (f32x4)0.f; }
  const ushort* w3b = w3t + (ocb3 + row16)*64 + quad*8;
  bf16x8 wa0 = *(const bf16x8*)(w3b);          // (tap0, ks0), oc-lo 16
  bf16x8 wa1 = *(const bf16x8*)(w3b + 1024);   // oc-hi 16
  #pragma unroll
  for (int tap = 0; tap < 9; ++tap) {
    const int t72 = ((tap/3)*10 + (tap%3))*72;     // compile-time after unroll
    #pragma unroll
    for (int ks = 0; ks < 2; ++ks) {
      // depth-1 weight prefetch; tap==8 overshoot reads workspace gap (discarded)
      const ushort* wn = w3b + ((ks == 0) ? (tap*8192 + 32) : ((tap+1)*8192));
      bf16x8 n0 = *(const bf16x8*)(wn);
      bf16x8 n1 = *(const bf16x8*)(wn + 1024);
      #pragma unroll
      for (int mt = 0; mt < 8; ++mt) {
        bf16x8 af = *(const bf16x8*)&xp[b3off[mt] + t72 + ks*32];
        c3[mt][0] = __builtin_amdgcn_mfma_f32_16x16x32_bf16(wa0, af, c3[mt][0], 0, 0, 0);
        c3[mt][1] = __builtin_amdgcn_mfma_f32_16x16x32_bf16(wa1, af, c3[mt][1], 0, 0, 0);
      }
      wa0 = n0; wa1 = n1;
    }
  }
  __syncthreads();   // ALIAS BARRIER: all xp reads done before h3p overwrites buf

  // ---- zero h3p halo ring: 2 img x 36 rows x 17 uint4 (disjoint from interior) ----
  for (int i = t; i < 1224; i += 256) {
    int img2 = (i >= 612), r = i - img2*612;
    int row = r/17, c = r - row*17;
    int rr = (row < 20) ? ((row < 10) ? row : row + 80)
                        : (((row-20) >> 1) + 1)*10 + ((row-20) & 1)*9;
    *(uint4*)&h3p[img2*13600 + rr*136 + c*8] = (uint4){0,0,0,0};
  }
  // ---- conv3 epilogue: D col=px(row16), row=oc(quad*4+r) -> h3p interior ----
  #pragma unroll
  for (int nt = 0; nt < 2; ++nt) {
    float4 bb = *(const float4*)&b3[ocb3 + nt*16 + quad*4];
    #pragma unroll
    for (int mt = 0; mt < 8; ++mt) {
      uint2 dd;
      dd.x = pack2(fmaxf(c3[mt][nt][0] + bb.x, 0.f), fmaxf(c3[mt][nt][1] + bb.y, 0.f));
      dd.y = pack2(fmaxf(c3[mt][nt][2] + bb.z, 0.f), fmaxf(c3[mt][nt][3] + bb.w, 0.f));
      *(uint2*)&h3p[r11c[mt] + ocb3 + nt*16 + quad*4] = dd;
    }
  }
  __syncthreads();

  // ---- conv4: wave = 64 oc (w*64, 4 frags) x 8 mt (2 img x 64 px) ----
  const int ocb4 = w*64;
  f32x4 c4[8][4];
  #pragma unroll
  for (int mt = 0; mt < 8; ++mt)
    #pragma unroll
    for (int nt = 0; nt < 4; ++nt) c4[mt][nt] = (f32x4)0.f;
  const ushort* w4b = w4t + (ocb4 + row16)*128 + quad*8;
  bf16x8 r4[4];
  #pragma unroll
  for (int nt = 0; nt < 4; ++nt) r4[nt] = *(const bf16x8*)(w4b + nt*2048);
  #pragma unroll
  for (int tap = 0; tap < 9; ++tap) {
    const int t136 = ((tap/3)*10 + (tap%3))*136;
    #pragma unroll
    for (int ks = 0; ks < 4; ++ks) {
      // depth-1 prefetch of next step's 4 weight frags; tap==8 overshoot in gap
      const ushort* wn = w4b + ((ks < 3) ? (tap*32768 + (ks+1)*32) : ((tap+1)*32768));
      bf16x8 nx[4];
      #pragma unroll
      for (int nt = 0; nt < 4; ++nt) nx[nt] = *(const bf16x8*)(wn + nt*2048);
      #pragma unroll
      for (int mt = 0; mt < 8; ++mt) {
        bf16x8 ax = *(const bf16x8*)&h3p[b4off[mt] + t136 + ks*32];
        #pragma unroll
        for (int nt = 0; nt < 4; ++nt)
          c4[mt][nt] = __builtin_amdgcn_mfma_f32_16x16x32_bf16(ax, r4[nt], c4[mt][nt], 0, 0, 0);
      }
      #pragma unroll
      for (int nt = 0; nt < 4; ++nt) r4[nt] = nx[nt];
    }
  }
  // ---- conv4 epilogue: D col=oc(row16), row=px(quad*4+r) -> h4c PING rows ----
  #pragma unroll
  for (int nt = 0; nt < 4; ++nt) {
    int oc = ocb4 + nt*16 + row16;
    float bv = b4[oc];
    #pragma unroll
    for (int mt = 0; mt < 8; ++mt) {
      int ig = bl*2 + (mt >> 2);             // ping-buffer row [0,2048)
      int px0 = (mt & 3)*16 + quad*4;
      uint2 dd;
      dd.x = pack2(fmaxf(c4[mt][nt][0] + bv, 0.f), fmaxf(c4[mt][nt][1] + bv, 0.f));
      dd.y = pack2(fmaxf(c4[mt][nt][2] + bv, 0.f), fmaxf(c4[mt][nt][3] + bv, 0.f));
      *(uint2*)&h4c[(size_t)ig*16384 + oc*64 + px0] = dd;
    }
  }
}

// ---------------- enc v2: z0 += h4c @ ewt^T, double-buffered LDS (1 barrier/iter,
// loads issued BEFORE MFMA so the ~160cy MFMA span covers load latency) +
// bijective XCD swizzle: grp=(bid&7)+8*(bid>>7), slice=grp&15, nb=grp>>4,
// mb=(bid>>3)&15 — co-locates the 16 same-B blocks of a group and the nb-pair
// sharing an A-tile on one XCD (64 blocks/XCD, all co-resident) -> B L2-resident,
// A traffic halved. Split-K=16, 128x128 tiles. LDS 64 KB -> still 2 blk/CU. -----
__global__ void __launch_bounds__(256) k_enc(const ushort* __restrict__ h4c,
    const ushort* __restrict__ ewt, float* __restrict__ z0, int img_base) {
  __shared__ ushort a_s[2][128*64];   // 32 KB
  __shared__ ushort b_s[2][128*64];   // 32 KB
  const int t = threadIdx.x, bid = blockIdx.x;
  const int grp = (bid & 7) + ((bid >> 7) << 3);   // [0,32)
  const int slice = grp & 15;
  const int nb    = grp >> 4;
  const int mb    = (bid >> 3) & 15;
  const int M0 = mb*128, N0 = nb*128;
  const int kbase = slice*1024;
  const int lane = t & 63, wv = t >> 6;
  const int quad = lane >> 4, row16 = lane & 15;
  const int mrow0 = (wv & 1)*64, ncol0 = (wv >> 1)*64;
  const int sr = lane >> 3, sp = lane & 7;

  f32x4 acc[4][4];
  #pragma unroll
  for (int mt = 0; mt < 4; ++mt)
    #pragma unroll
    for (int nt = 0; nt < 4; ++nt) acc[mt][nt] = (f32x4)0.f;

  // prologue: stage kt=0 into buffer 0
  #pragma unroll
  for (int u = 0; u < 4; ++u) {
    int r = wv*32 + u*8 + sr;
    int c = sp ^ (r & 7);
    gload_lds16(&h4c[(size_t)(M0 + r)*16384 + kbase + c*8], &a_s[0][(wv*32 + u*8)*64]);
    gload_lds16(&ewt[(size_t)(N0 + r)*16384 + kbase + c*8], &b_s[0][(wv*32 + u*8)*64]);
  }
  __syncthreads();

  int cur = 0;
  for (int kt = 0; kt < 16; ++kt) {
    if (kt < 15) {                       // issue next K-step's loads first
      const int k1 = kbase + (kt + 1)*64;
      #pragma unroll
      for (int u = 0; u < 4; ++u) {
        int r = wv*32 + u*8 + sr;
        int c = sp ^ (r & 7);
        gload_lds16(&h4c[(size_t)(M0 + r)*16384 + k1 + c*8], &a_s[cur^1][(wv*32 + u*8)*64]);
        gload_lds16(&ewt[(size_t)(N0 + r)*16384 + k1 + c*8], &b_s[cur^1][(wv*32 + u*8)*64]);
      }
    }
    #pragma unroll
    for (int ks = 0; ks < 2; ++ks) {
      bf16x8 af[4], bf[4];
      #pragma unroll
      for (int mt = 0; mt < 4; ++mt) {
        int r = mrow0 + mt*16 + row16;
        int p = (ks*4 + quad) ^ (r & 7);
        af[mt] = *(const bf16x8*)&a_s[cur][r*64 + p*8];
      }
      #pragma unroll
      for (int nt = 0; nt < 4; ++nt) {
        int r = ncol0 + nt*16 + row16;
        int p = (ks*4 + quad) ^ (r & 7);
        bf[nt] = *(const bf16x8*)&b_s[cur][r*64 + p*8];
      }
      #pragma unroll
      for (int mt = 0; mt < 4; ++mt)
        #pragma unroll
        for (int nt = 0; nt < 4; ++nt)
          acc[mt][nt] = __builtin_amdgcn_mfma_f32_16x16x32_bf16(af[mt], bf[nt], acc[mt][nt], 0, 0, 0);
    }
    __syncthreads();   // drains this iter's gloads (next buf ready) + all ds_reads
    cur ^= 1;
  }
  #pragma unroll
  for (int mt = 0; mt < 4; ++mt) {
    int mrow = M0 + mrow0 + mt*16 + quad*4;
    #pragma unroll
    for (int nt = 0; nt < 4; ++nt) {
      int col = N0 + ncol0 + nt*16 + row16;
      #pragma unroll
      for (int r = 0; r < 4; ++r)
        atomicAdd(&z0[(size_t)(img_base + mrow + r)*256 + col], acc[mt][nt][r]);
    }
  }
}

// ---------------- post v4: fully-fused MFMA tail, 16 img/block, grid 256;
// weff + gate + pn2 + gn2 staged to LDS (kills all per-thread scalar global
// loads in phase-2 / softmax / classifier tail). ------------------------------
__global__ void __launch_bounds__(256) k_post2(const float* __restrict__ z0,
    const float* __restrict__ enc_b, const float* __restrict__ nfb,
    const ushort* __restrict__ nfwt, const ushort* __restrict__ pjd,
    const ushort* __restrict__ gjd, const ushort* __restrict__ ptb,
    const float* __restrict__ ws, const float* __restrict__ clf_b,
    float* __restrict__ out) {
  __shared__ ushort zin[16*264];   // 8448 B
  __shared__ ushort zS [16*264];   // 8448 B
  __shared__ float  Df [16*264];   // 16896 B (l / blended)
  __shared__ ushort wS [16*264];   // 8448 B
  __shared__ float  weffS[2560];   // 10240 B
  __shared__ float  gateS[256], pnS[256], gnS[256];   // 3072 B
  __shared__ float  z2s[16];
  const int t = threadIdx.x, bx = blockIdx.x;
  const int img0 = bx*16;
  gateS[t] = ws[OFF_GATE + t];
  pnS[t]   = ws[OFF_PN2 + t];
  gnS[t]   = ws[OFF_GN2 + t];
  #pragma unroll
  for (int u = 0; u < 10; ++u)
    weffS[t + u*256] = ws[OFF_WEFF + t + u*256];
  #pragma unroll
  for (int u = 0; u < 16; ++u) {
    int i = t + u*256;
    int im = i >> 8, d = i & 255;
    zin[im*264 + d] = f2bf(z0[(size_t)(img0 + im)*256 + d] + enc_b[d]);
  }
  __syncthreads();

  const int lane = t & 63, w = t >> 6;
  const int quad = lane >> 4, row16 = lane & 15;
  const int n0 = w*64;

  // ---- phase 1: z = zin @ nfw^T + nfb ----
  f32x4 zC[4];
  #pragma unroll
  for (int nt = 0; nt < 4; ++nt) zC[nt] = (f32x4)0.f;
  #pragma unroll
  for (int ks = 0; ks < 8; ++ks) {
    bf16x8 az = *(const bf16x8*)&zin[row16*264 + ks*32 + quad*8];
    #pragma unroll
    for (int nt = 0; nt < 4; ++nt) {
      bf16x8 bw = *(const bf16x8*)&nfwt[(n0 + nt*16 + row16)*256 + ks*32 + quad*8];
      zC[nt] = __builtin_amdgcn_mfma_f32_16x16x32_bf16(az, bw, zC[nt], 0, 0, 0);
    }
  }
  #pragma unroll
  for (int nt = 0; nt < 4; ++nt) {
    int n = n0 + nt*16 + row16;
    float nb = nfb[n];
    #pragma unroll
    for (int r = 0; r < 4; ++r)
      zS[(quad*4 + r)*264 + n] = f2bf(zC[nt][r] + nb);
  }
  __syncthreads();

  {
    int im = t >> 4, jg = t & 15;
    float s = 0.f;
    #pragma unroll
    for (int q = 0; q < 16; ++q) {
      float v = bf2f(zS[im*264 + jg + 16*q]);
      s += v*v;
    }
    #pragma unroll
    for (int off = 8; off; off >>= 1) s += __shfl_xor(s, off, 16);
    if (jg == 0) z2s[im] = s;
  }
  __syncthreads();

  // ---- phase 2: dp/dg = z @ protos^T / grid^T -> logits l ----
  f32x4 dpC[4], dgC[4];
  #pragma unroll
  for (int nt = 0; nt < 4; ++nt) { dpC[nt] = (f32x4)0.f; dgC[nt] = (f32x4)0.f; }
  #pragma unroll
  for (int ks = 0; ks < 8; ++ks) {
    bf16x8 az = *(const bf16x8*)&zS[row16*264 + ks*32 + quad*8];
    #pragma unroll
    for (int nt = 0; nt < 4; ++nt) {
      int j = n0 + nt*16 + row16;
      bf16x8 bp = *(const bf16x8*)&pjd[j*256 + ks*32 + quad*8];
      bf16x8 bg = *(const bf16x8*)&gjd[j*256 + ks*32 + quad*8];
      dpC[nt] = __builtin_amdgcn_mfma_f32_16x16x32_bf16(az, bp, dpC[nt], 0, 0, 0);
      dgC[nt] = __builtin_amdgcn_mfma_f32_16x16x32_bf16(az, bg, dgC[nt], 0, 0, 0);
    }
  }
  {
    float temp = ws[OFF_TEMP];
    #pragma unroll
    for (int nt = 0; nt < 4; ++nt) {
      int j = n0 + nt*16 + row16;
      float pn = pnS[j], gn = gnS[j];
      #pragma unroll
      for (int r = 0; r < 4; ++r) {
        int im = quad*4 + r;
        float z2 = z2s[im];
        float d2p = z2 + pn - 2.f*dpC[nt][r];
        float d2g = z2 + gn - 2.f*dgC[nt][r];
        float l = -(sqrtf(fmaxf(d2p, 0.f)) + sqrtf(fmaxf(d2g, 0.f)))/temp;
        Df[im*264 + j] = l;
      }
    }
  }
  __syncthreads();

  // ---- softmax + gate + renorm -> wS bf16 ----
  {
    int im = t >> 4, jg = t & 15;
    float m = -1e30f;
    #pragma unroll
    for (int q = 0; q < 16; ++q) m = fmaxf(m, Df[im*264 + jg + 16*q]);
    #pragma unroll
    for (int off = 8; off; off >>= 1) m = fmaxf(m, __shfl_xor(m, off, 16));
    float E = 0.f, S = 0.f, ev[16], gv[16];
    #pragma unroll
    for (int q = 0; q < 16; ++q) {
      int j = jg + 16*q;
      float e = expf(Df[im*264 + j] - m);
      float g = gateS[j];
      ev[q] = e; gv[q] = g;
      E += e; S += e*g;
    }
    #pragma unroll
    for (int off = 8; off; off >>= 1) {
      E += __shfl_xor(E, off, 16);
      S += __shfl_xor(S, off, 16);
    }
    float inv = 1.f/(S + 1e-8f*E);
    #pragma unroll
    for (int q = 0; q < 16; ++q)
      wS[im*264 + jg + 16*q] = f2bf(ev[q]*gv[q]*inv);
  }
  __syncthreads();

  // ---- phase 3: blended = w @ protos ----
  f32x4 blC[4];
  #pragma unroll
  for (int nt = 0; nt < 4; ++nt) blC[nt] = (f32x4)0.f;
  #pragma unroll
  for (int ks = 0; ks < 8; ++ks) {
    bf16x8 aw = *(const bf16x8*)&wS[row16*264 + ks*32 + quad*8];
    #pragma unroll
    for (int nt = 0; nt < 4; ++nt) {
      bf16x8 bp = *(const bf16x8*)&ptb[(n0 + nt*16 + row16)*256 + ks*32 + quad*8];
      blC[nt] = __builtin_amdgcn_mfma_f32_16x16x32_bf16(aw, bp, blC[nt], 0, 0, 0);
    }
  }
  #pragma unroll
  for (int nt = 0; nt < 4; ++nt) {
    int d = n0 + nt*16 + row16;
    #pragma unroll
    for (int r = 0; r < 4; ++r)
      Df[(quad*4 + r)*264 + d] = blC[nt][r];
  }
  __syncthreads();

  if (t < 160) {
    int im = t/10, c = t - im*10;
    float s = clf_b[c];
    for (int d = 0; d < 256; ++d)
      s += Df[im*264 + d]*weffS[d*10 + c];
    out[(size_t)(img0 + im)*10 + c] = s;
  }
}

extern "C" void kernel_launch(void* const* d_in, const int* in_sizes, int n_in,
                              void* d_out, int out_size, void* d_ws, size_t ws_size,
                              hipStream_t stream) {
  (void)in_sizes; (void)n_in; (void)out_size; (void)ws_size;
  const float* x      = (const float*)d_in[0];
  const float* c1w    = (const float*)d_in[2];
  const float* c1b    = (const float*)d_in[3];
  const float* c2w    = (const float*)d_in[4];
  const float* c2b    = (const float*)d_in[5];
  const float* c3w    = (const float*)d_in[6];
  const float* c3b    = (const float*)d_in[7];
  const float* c4w    = (const float*)d_in[8];
  const float* c4b    = (const float*)d_in[9];
  const float* encw   = (const float*)d_in[10];
  const float* encb   = (const float*)d_in[11];
  // d_in[12..17] dead: softmax over a single node == 1 exactly
  const float* clfw   = (const float*)d_in[18];
  const float* clfb   = (const float*)d_in[19];
  const float* nfw    = (const float*)d_in[20];
  const float* nfb    = (const float*)d_in[21];
  const float* protos = (const float*)d_in[22];
  const float* gridp  = (const float*)d_in[23];
  const float* traw   = (const float*)d_in[24];
  const float* gatel  = (const float*)d_in[25];

  float*  ws   = (float*)d_ws;
  float*  w1t  = ws + OFF_W1T;
  ushort* w2t  = (ushort*)((char*)d_ws + OFF_W2T_BYTES);
  ushort* w3t  = (ushort*)((char*)d_ws + OFF_W3T_BYTES);
  ushort* w4t  = (ushort*)((char*)d_ws + OFF_W4T_BYTES);
  ushort* ewt  = (ushort*)((char*)d_ws + OFF_EWT_BYTES);
  ushort* nfwt = (ushort*)((char*)d_ws + OFF_NFWT_BYTES);
  ushort* pjd  = (ushort*)((char*)d_ws + OFF_PJD_BYTES);
  ushort* gjd  = (ushort*)((char*)d_ws + OFF_GJD_BYTES);
  ushort* ptb  = (ushort*)((char*)d_ws + OFF_PTB_BYTES);
  ushort* h4c  = (ushort*)((char*)d_ws + OFF_A_BYTES);
  ushort* h2c  = (ushort*)((char*)d_ws + OFF_B_BYTES);
  float*  z0   = (float*) ((char*)d_ws + OFF_Z0_BYTES);
  float*  out  = (float*)d_out;

  hipLaunchKernelGGL(k_init, dim3(2688), dim3(TPB), 0, stream,
                     encw, ewt, c1w, c2w, c3w, c4w, w1t, w2t, w3t, w4t,
                     protos, gridp, gatel, traw, clfw, ws, z0,
                     nfw, nfwt, pjd, gjd, ptb);
  hipLaunchKernelGGL(k_conv12, dim3(4096), dim3(TPB), 0, stream, x, w1t, c1b, w2t, c2b, h2c);
  for (int c = 0; c < 2; ++c) {
    hipLaunchKernelGGL(k_conv34, dim3(1024), dim3(TPB), 0, stream,
                       h2c, c3b, c4b, w3t, w4t, h4c, c*2048);
    hipLaunchKernelGGL(k_enc, dim3(512), dim3(TPB), 0, stream, h4c, ewt, z0, c*2048);
  }
  hipLaunchKernelGGL(k_post2, dim3(256), dim3(TPB), 0, stream,
                     z0, encb, nfb, nfwt, pjd, gjd, ptb, ws, clfb, out);
}

// Round 10
// 518.942 us; speedup vs baseline: 1.2730x; 1.0023x over previous
//
#include <hip/hip_runtime.h>
#include <math.h>

#define TPB 256

typedef __attribute__((ext_vector_type(8))) short bf16x8;
typedef __attribute__((ext_vector_type(4))) float f32x4;
typedef __attribute__((ext_vector_type(2))) float f32x2;

// ---------------- workspace layout ----------------
// aux (fp32), float offsets:
#define OFF_PN2   0          // 256
#define OFF_GN2   256        // 256
#define OFF_GATE  512        // 256
#define OFF_TEMP  768        // 1
#define OFF_WEFF  1024       // 2560
#define OFF_W1T   3584       // 2400 fp32: w1t[tap<75][oc<32]
// bf16 weight tables (byte offsets):
#define OFF_W2T_BYTES 737280ul    // 9*64*32   bf16
#define OFF_W3T_BYTES 786432ul    // 9*128*64  bf16
#define OFF_W4T_BYTES 983040ul    // 9*256*128 bf16
#define OFF_EWT_BYTES 2097152ul   // ewt[n=256][k=16384] bf16 = 8 MiB
// post-stage bf16 tables:
#define OFF_NFWT_BYTES 10485760ul // nfwt[n=256][k=256] bf16 = 128 KiB
#define OFF_PJD_BYTES  10616832ul // protos[j][d] bf16
#define OFF_GJD_BYTES  10747904ul // grid[j][d] bf16
#define OFF_PTB_BYTES  10878976ul // protosT[d][j] bf16
// big regions (byte offsets):
#define OFF_A_BYTES   12582912ul  // h4c ping buffer: 2048 img x 32KB = 64 MiB
#define OFF_B_BYTES   (OFF_A_BYTES + 67108864ul)   // h2c: 4096 img x 8KB = 32 MiB
#define OFF_Z0_BYTES  (OFF_B_BYTES + 33554432ul)   // z0: 4096x256 f32 = 4 MiB
// total ~112 MiB

// ---------------- bf16 helpers ----------------
__device__ __forceinline__ float bf2f(ushort u) {
  return __uint_as_float(((unsigned)u) << 16);
}
__device__ __forceinline__ ushort f2bf(float f) {   // RNE
  unsigned x = __float_as_uint(f);
  return (ushort)((x + 0x7fffu + ((x >> 16) & 1u)) >> 16);
}
__device__ __forceinline__ unsigned pack2(float a, float b) {
  return (unsigned)f2bf(a) | ((unsigned)f2bf(b) << 16);
}

// async global->LDS, 16B per lane; lds dest = wave-uniform base + lane*16
__device__ __forceinline__ void gload_lds16(const ushort* g, ushort* l) {
  __builtin_amdgcn_global_load_lds(
      (const __attribute__((address_space(1))) unsigned int*)g,
      (__attribute__((address_space(3))) unsigned int*)l, 16, 0, 0);
}

// ---------------- block reductions ----------------
__device__ __forceinline__ float block_sum(float v, float* red) {
  #pragma unroll
  for (int off = 32; off > 0; off >>= 1) v += __shfl_down(v, off, 64);
  int wid = threadIdx.x >> 6;
  __syncthreads();
  if ((threadIdx.x & 63) == 0) red[wid] = v;
  __syncthreads();
  return red[0] + red[1] + red[2] + red[3];
}

// ---------------- k_init: merged setup + prep + prep2 + trans ------------------
// blocks [0,1024):    trans  (enc_w -> ewt bf16 transpose)
// blocks [1024,2176): prep   (conv weight tables)
// blocks [2176,2432): setup  (norms, gate, temp, weff, z0 zero)
// blocks [2432,2688): prep2  (post-stage bf16 tables)
__global__ void __launch_bounds__(256) k_init(
    const float* __restrict__ ew,    ushort* __restrict__ ewt,
    const float* __restrict__ w1,    const float* __restrict__ w2,
    const float* __restrict__ w3,    const float* __restrict__ w4,
    float* __restrict__ w1t, ushort* __restrict__ w2t,
    ushort* __restrict__ w3t, ushort* __restrict__ w4t,
    const float* __restrict__ protos, const float* __restrict__ gridp,
    const float* __restrict__ gate_logits, const float* __restrict__ temp_raw,
    const float* __restrict__ clf_w, float* __restrict__ ws,
    float* __restrict__ z0,
    const float* __restrict__ nfw, ushort* __restrict__ nfwt,
    ushort* __restrict__ pjd, ushort* __restrict__ gjd,
    ushort* __restrict__ ptb) {
  __shared__ float tile[64][65];
  __shared__ float red[4];
  const int bx = blockIdx.x, t = threadIdx.x;

  if (bx < 1024) {                 // ---- trans ----
    int kb = bx & 255, nb = bx >> 8;
    #pragma unroll
    for (int i = 0; i < 16; ++i) {
      int idx = t + i*256, k = idx >> 6, n = idx & 63;
      tile[k][n] = ew[(size_t)(kb*64 + k)*256 + nb*64 + n];
    }
    __syncthreads();
    #pragma unroll
    for (int i = 0; i < 16; ++i) {
      int idx = t + i*256, n = idx >> 6, k = idx & 63;
      ewt[(size_t)(nb*64 + n)*16384 + kb*64 + k] = f2bf(tile[k][n]);
    }
    return;
  }
  if (bx < 2176) {                 // ---- prep ----
    int idx = (bx - 1024)*256 + t;
    if (idx < 2400) {
      int tap = idx >> 5, oc = idx & 31;
      w1t[idx] = w1[oc*75 + tap];
    }
    if (idx < 18432) {
      int tap = idx >> 11, r = idx & 2047, oc = r >> 5, ic = r & 31;
      w2t[idx] = f2bf(w2[oc*288 + ic*9 + tap]);
    }
    if (idx < 73728) {
      int tap = idx >> 13, r = idx & 8191, oc = r >> 6, ic = r & 63;
      w3t[idx] = f2bf(w3[oc*576 + ic*9 + tap]);
    }
    if (idx < 294912) {
      int tap = idx >> 15, r = idx & 32767, oc = r >> 7, ic = r & 127;
      w4t[idx] = f2bf(w4[oc*1152 + ic*9 + tap]);
    }
    return;
  }
  if (bx < 2432) {                 // ---- setup ----
    int b = bx - 2176;
    #pragma unroll
    for (int u = 0; u < 16; ++u) z0[(size_t)u*65536 + b*256 + t] = 0.f;
    float pv = protos[b*256 + t];
    float gv = gridp [b*256 + t];
    float sp = block_sum(pv*pv, red);
    float sg = block_sum(gv*gv, red);
    if (t == 0) {
      ws[OFF_PN2 + b] = sp;
      ws[OFF_GN2 + b] = sg;
      ws[OFF_GATE + b] = 1.f/(1.f + expf(-gate_logits[b]));
    }
    if (b == 0) {
      for (int i = t; i < 2560; i += TPB) {
        int d = i/10, c = i%10;
        ws[OFF_WEFF + i] = clf_w[d*10+c] + clf_w[(256+d)*10+c]
                         + clf_w[(512+d)*10+c] + clf_w[(768+d)*10+c];
      }
      if (t == 0) {
        float s = 1.f/(1.f + expf(-temp_raw[0]));
        ws[OFF_TEMP] = s*(1.f - 0.001f) + 0.001f;
      }
    }
    return;
  }
  {                                // ---- prep2 ----
    int idx = (bx - 2432)*256 + t;   // 65536
    int a = idx >> 8, b = idx & 255;
    nfwt[idx] = f2bf(nfw[b*256 + a]);     // [n][k] = nfw[k][n]
    pjd [idx] = f2bf(protos[idx]);        // [j][d]
    gjd [idx] = f2bf(gridp[idx]);         // [j][d]
    ptb [idx] = f2bf(protos[b*256 + a]);  // [d][j] = protos[j][d]
  }
}

// ---------------- conv1+conv2 fused v5: x staged to LDS (12.7 KB, pad-33 rows)
// conv1's 75 per-thread scalar GLOBAL loads become ds_read_b32 (global traffic
// 75x -> 3x float4/thread, coalesced). Values bit-identical -> absmax unchanged.
// Staging barrier also closes the latent xs-zero vs conv1-write race. ----------
__global__ void __launch_bounds__(256) k_conv12(const float* __restrict__ x,
    const float* __restrict__ w1t, const float* __restrict__ b1,
    const ushort* __restrict__ w2t, const float* __restrict__ b2,
    ushort* __restrict__ h2c) {
  __shared__ ushort xs[17*17*40];   // 23120 B (conv2 input, bf16 packed)
  __shared__ float  xf[3*32*33];    // 12672 B (conv1 input, pad stride 33)
  int b = blockIdx.x, t = threadIdx.x;
  for (int i = t; i < 5780; i += TPB) ((unsigned*)xs)[i] = 0u;
  const float* xb = x + (size_t)b*3072;
  // ---- stage x -> xf: 3 coalesced float4 loads per thread ----
  #pragma unroll
  for (int i = 0; i < 3; ++i) {
    int idx = (t + i*256)*4;                 // 0..3068 step 4, covers 3072 floats
    float4 v = *(const float4*)&xb[idx];
    int ic = idx >> 10, rem = idx & 1023, iy = rem >> 5, ix = rem & 31;
    float* dst = &xf[ic*1056 + iy*33 + ix];
    dst[0] = v.x; dst[1] = v.y; dst[2] = v.z; dst[3] = v.w;
  }
  __syncthreads();

  if (t < 225) {               // conv1: one px per thread, all 32 oc, packed f32
    int oy = t/15, ox = t%15;
    f32x2 acc[16];
    #pragma unroll
    for (int o = 0; o < 16; ++o) acc[o] = *(const f32x2*)&b1[2*o];
    for (int ic = 0; ic < 3; ++ic) {
      const int icb = ic*1056;
      #pragma unroll
      for (int ky = 0; ky < 5; ++ky) {
        int iy = 2*oy - 1 + ky;
        bool rok = (unsigned)iy < 32u;
        int rbase = icb + (rok ? iy*33 : 0);
        #pragma unroll
        for (int kx = 0; kx < 5; ++kx) {
          int ix = 2*ox - 1 + kx;
          bool ok = rok && ((unsigned)ix < 32u);
          float xv = xf[rbase + (ok ? ix : 0)];
          xv = ok ? xv : 0.f;
          f32x2 xv2 = {xv, xv};
          const float* wrow = &w1t[(ic*25 + ky*5 + kx)*32];   // wave-uniform -> s_load
          #pragma unroll
          for (int g = 0; g < 8; ++g) {
            f32x2 wlo = {wrow[4*g+0], wrow[4*g+1]};
            f32x2 whi = {wrow[4*g+2], wrow[4*g+3]};
            acc[2*g]   += xv2*wlo;
            acc[2*g+1] += xv2*whi;
          }
        }
      }
    }
    unsigned pk[16];
    #pragma unroll
    for (int g = 0; g < 16; ++g)
      pk[g] = pack2(fmaxf(acc[g].x, 0.f), fmaxf(acc[g].y, 0.f));
    ushort* cell = &xs[((oy+1)*17 + (ox+1))*40];
    #pragma unroll
    for (int q = 0; q < 4; ++q) *(uint4*)(cell + q*8) = ((uint4*)pk)[q];
  }
  __syncthreads();

  // conv2 MFMA (swapped: oc-in-regs): wave w -> oc [w*16, w*16+16)
  const int lane = t & 63, w = t >> 6;
  const int quad = lane >> 4, row16 = lane & 15;
  f32x4 acc2[4];
  #pragma unroll
  for (int mt = 0; mt < 4; ++mt) acc2[mt] = (f32x4)0.f;
  #pragma unroll
  for (int ky = 0; ky < 3; ++ky)
    #pragma unroll
    for (int kx = 0; kx < 3; ++kx) {
      int tap = ky*3 + kx;
      bf16x8 bf = *(const bf16x8*)&w2t[tap*2048 + (w*16 + row16)*32 + quad*8];
      #pragma unroll
      for (int mt = 0; mt < 4; ++mt) {
        int px = mt*16 + row16;
        int iy = 2*(px >> 3) + ky, ix = 2*(px & 7) + kx;
        bf16x8 af = *(const bf16x8*)&xs[(iy*17 + ix)*40 + quad*8];
        acc2[mt] = __builtin_amdgcn_mfma_f32_16x16x32_bf16(bf, af, acc2[mt], 0, 0, 0);
      }
    }
  float4 bb = *(const float4*)&b2[w*16 + quad*4];
  #pragma unroll
  for (int mt = 0; mt < 4; ++mt) {
    int px = mt*16 + row16;
    uint2 dd;
    dd.x = pack2(fmaxf(acc2[mt][0] + bb.x, 0.f), fmaxf(acc2[mt][1] + bb.y, 0.f));
    dd.y = pack2(fmaxf(acc2[mt][2] + bb.z, 0.f), fmaxf(acc2[mt][3] + bb.w, 0.f));
    *(uint2*)&h2c[(size_t)b*4096 + px*64 + w*16 + quad*4] = dd;
  }
}

// ---------------- conv3+conv4 fused v12 (PROVEN 115us): v9 structure + ping fix.
// 256 thr, 4 waves, 2 img/block, launch_bounds(256,2) -> 256-reg budget
// (124 arch + 128 acc, NO spill), halo-in-LDS (10x10 rows, zeroed ring,
// strides 72/136), depth-1 weight prefetch with 16/32 MFMA per step.
// conv4 writes h4c PING rows [0,2048): ig = bl*2 + img.
__global__ void __launch_bounds__(256, 2) k_conv34(const ushort* __restrict__ h2c,
    const float* __restrict__ b3, const float* __restrict__ b4,
    const ushort* __restrict__ w3t, const ushort* __restrict__ w4t,
    ushort* __restrict__ h4c, int img_base) {
  // xp  = [img<2][row<100][72]   (14400 ushorts, 28.8 KB)  -- conv3 input
  // h3p = [img<2][row<100][136]  (27200 ushorts, 54.4 KB)  -- aliased, conv4 input
  __shared__ __attribute__((aligned(16))) ushort buf[27200];
  ushort* xp  = buf;
  ushort* h3p = buf;
  const int bl = blockIdx.x, t = threadIdx.x;

  // ---- zero xp halo ring: 2 img x 36 rows x 9 uint4 ----
  for (int i = t; i < 648; i += 256) {
    int img = (i >= 324), r = i - img*324;
    int row = r/9, c = r - row*9;
    int rr = (row < 20) ? ((row < 10) ? row : row + 80)
                        : (((row-20) >> 1) + 1)*10 + ((row-20) & 1)*9;
    *(uint4*)&xp[img*7200 + rr*72 + c*8] = (uint4){0,0,0,0};
  }
  // ---- stage conv3 input interior (disjoint from ring; no barrier needed) ----
  #pragma unroll
  for (int u = 0; u < 4; ++u) {
    int i = t + u*256;
    int img = i >> 9, px = (i >> 3) & 63, icg = i & 7;
    bf16x8 v = *(const bf16x8*)&h2c[(size_t)(img_base + bl*2 + img)*4096 + px*64 + icg*8];
    int row = ((px >> 3) + 1)*10 + (px & 7) + 1;
    *(bf16x8*)&xp[img*7200 + row*72 + icg*8] = v;
  }
  __syncthreads();

  const int lane = t & 63, w = t >> 6;
  const int quad = lane >> 4, row16 = lane & 15;

  // per-mt LDS base offsets (ushort units); mt = img*4 + px-group
  int b3off[8], b4off[8], r11c[8];
  #pragma unroll
  for (int mt = 0; mt < 8; ++mt) {
    int px = (mt & 3)*16 + row16;
    int r00 = (px >> 3)*10 + (px & 7);     // halo-corner row for tap (0,0)
    int img = mt >> 2;
    b3off[mt] = img*7200  + r00*72  + quad*8;
    b4off[mt] = img*13600 + r00*136 + quad*8;
    r11c[mt]  = img*13600 + (r00 + 11)*136;   // interior row for epilogue
  }

  // ---- conv3: wave = 32 oc (w*32, 2 frags) x 8 mt (2 img x 64 px) ----
  const int ocb3 = w*32;
  f32x4 c3[8][2];
  #pragma unroll
  for (int mt = 0; mt < 8; ++mt) { c3[mt][0] = (f32x4)0.f; c3[mt][1] = (f32x4)0.f; }
  const ushort* w3b = w3t + (ocb3 + row16)*64 + quad*8;
  bf16x8 wa0 = *(const bf16x8*)(w3b);          // (tap0, ks0), oc-lo 16
  bf16x8 wa1 = *(const bf16x8*)(w3b + 1024);   // oc-hi 16
  #pragma unroll
  for (int tap = 0; tap < 9; ++tap) {
    const int t72 = ((tap/3)*10 + (tap%3))*72;     // compile-time after unroll
    #pragma unroll
    for (int ks = 0; ks < 2; ++ks) {
      // depth-1 weight prefetch; tap==8 overshoot reads workspace gap (discarded)
      const ushort* wn = w3b + ((ks == 0) ? (tap*8192 + 32) : ((tap+1)*8192));
      bf16x8 n0 = *(const bf16x8*)(wn);
      bf16x8 n1 = *(const bf16x8*)(wn + 1024);
      #pragma unroll
      for (int mt = 0; mt < 8; ++mt) {
        bf16x8 af = *(const bf16x8*)&xp[b3off[mt] + t72 + ks*32];
        c3[mt][0] = __builtin_amdgcn_mfma_f32_16x16x32_bf16(wa0, af, c3[mt][0], 0, 0, 0);
        c3[mt][1] = __builtin_amdgcn_mfma_f32_16x16x32_bf16(wa1, af, c3[mt][1], 0, 0, 0);
      }
      wa0 = n0; wa1 = n1;
    }
  }
  __syncthreads();   // ALIAS BARRIER: all xp reads done before h3p overwrites buf

  // ---- zero h3p halo ring: 2 img x 36 rows x 17 uint4 (disjoint from interior) ----
  for (int i = t; i < 1224; i += 256) {
    int img2 = (i >= 612), r = i - img2*612;
    int row = r/17, c = r - row*17;
    int rr = (row < 20) ? ((row < 10) ? row : row + 80)
                        : (((row-20) >> 1) + 1)*10 + ((row-20) & 1)*9;
    *(uint4*)&h3p[img2*13600 + rr*136 + c*8] = (uint4){0,0,0,0};
  }
  // ---- conv3 epilogue: D col=px(row16), row=oc(quad*4+r) -> h3p interior ----
  #pragma unroll
  for (int nt = 0; nt < 2; ++nt) {
    float4 bb = *(const float4*)&b3[ocb3 + nt*16 + quad*4];
    #pragma unroll
    for (int mt = 0; mt < 8; ++mt) {
      uint2 dd;
      dd.x = pack2(fmaxf(c3[mt][nt][0] + bb.x, 0.f), fmaxf(c3[mt][nt][1] + bb.y, 0.f));
      dd.y = pack2(fmaxf(c3[mt][nt][2] + bb.z, 0.f), fmaxf(c3[mt][nt][3] + bb.w, 0.f));
      *(uint2*)&h3p[r11c[mt] + ocb3 + nt*16 + quad*4] = dd;
    }
  }
  __syncthreads();

  // ---- conv4: wave = 64 oc (w*64, 4 frags) x 8 mt (2 img x 64 px) ----
  const int ocb4 = w*64;
  f32x4 c4[8][4];
  #pragma unroll
  for (int mt = 0; mt < 8; ++mt)
    #pragma unroll
    for (int nt = 0; nt < 4; ++nt) c4[mt][nt] = (f32x4)0.f;
  const ushort* w4b = w4t + (ocb4 + row16)*128 + quad*8;
  bf16x8 r4[4];
  #pragma unroll
  for (int nt = 0; nt < 4; ++nt) r4[nt] = *(const bf16x8*)(w4b + nt*2048);
  #pragma unroll
  for (int tap = 0; tap < 9; ++tap) {
    const int t136 = ((tap/3)*10 + (tap%3))*136;
    #pragma unroll
    for (int ks = 0; ks < 4; ++ks) {
      // depth-1 prefetch of next step's 4 weight frags; tap==8 overshoot in gap
      const ushort* wn = w4b + ((ks < 3) ? (tap*32768 + (ks+1)*32) : ((tap+1)*32768));
      bf16x8 nx[4];
      #pragma unroll
      for (int nt = 0; nt < 4; ++nt) nx[nt] = *(const bf16x8*)(wn + nt*2048);
      #pragma unroll
      for (int mt = 0; mt < 8; ++mt) {
        bf16x8 ax = *(const bf16x8*)&h3p[b4off[mt] + t136 + ks*32];
        #pragma unroll
        for (int nt = 0; nt < 4; ++nt)
          c4[mt][nt] = __builtin_amdgcn_mfma_f32_16x16x32_bf16(ax, r4[nt], c4[mt][nt], 0, 0, 0);
      }
      #pragma unroll
      for (int nt = 0; nt < 4; ++nt) r4[nt] = nx[nt];
    }
  }
  // ---- conv4 epilogue: D col=oc(row16), row=px(quad*4+r) -> h4c PING rows ----
  #pragma unroll
  for (int nt = 0; nt < 4; ++nt) {
    int oc = ocb4 + nt*16 + row16;
    float bv = b4[oc];
    #pragma unroll
    for (int mt = 0; mt < 8; ++mt) {
      int ig = bl*2 + (mt >> 2);             // ping-buffer row [0,2048)
      int px0 = (mt & 3)*16 + quad*4;
      uint2 dd;
      dd.x = pack2(fmaxf(c4[mt][nt][0] + bv, 0.f), fmaxf(c4[mt][nt][1] + bv, 0.f));
      dd.y = pack2(fmaxf(c4[mt][nt][2] + bv, 0.f), fmaxf(c4[mt][nt][3] + bv, 0.f));
      *(uint2*)&h4c[(size_t)ig*16384 + oc*64 + px0] = dd;
    }
  }
}

// ---------------- enc v2: z0 += h4c @ ewt^T, double-buffered LDS (1 barrier/iter,
// loads issued BEFORE MFMA so the ~160cy MFMA span covers load latency) +
// bijective XCD swizzle. Split-K=16, 128x128 tiles. LDS 64 KB -> 2 blk/CU. -----
__global__ void __launch_bounds__(256) k_enc(const ushort* __restrict__ h4c,
    const ushort* __restrict__ ewt, float* __restrict__ z0, int img_base) {
  __shared__ ushort a_s[2][128*64];   // 32 KB
  __shared__ ushort b_s[2][128*64];   // 32 KB
  const int t = threadIdx.x, bid = blockIdx.x;
  const int grp = (bid & 7) + ((bid >> 7) << 3);   // [0,32)
  const int slice = grp & 15;
  const int nb    = grp >> 4;
  const int mb    = (bid >> 3) & 15;
  const int M0 = mb*128, N0 = nb*128;
  const int kbase = slice*1024;
  const int lane = t & 63, wv = t >> 6;
  const int quad = lane >> 4, row16 = lane & 15;
  const int mrow0 = (wv & 1)*64, ncol0 = (wv >> 1)*64;
  const int sr = lane >> 3, sp = lane & 7;

  f32x4 acc[4][4];
  #pragma unroll
  for (int mt = 0; mt < 4; ++mt)
    #pragma unroll
    for (int nt = 0; nt < 4; ++nt) acc[mt][nt] = (f32x4)0.f;

  // prologue: stage kt=0 into buffer 0
  #pragma unroll
  for (int u = 0; u < 4; ++u) {
    int r = wv*32 + u*8 + sr;
    int c = sp ^ (r & 7);
    gload_lds16(&h4c[(size_t)(M0 + r)*16384 + kbase + c*8], &a_s[0][(wv*32 + u*8)*64]);
    gload_lds16(&ewt[(size_t)(N0 + r)*16384 + kbase + c*8], &b_s[0][(wv*32 + u*8)*64]);
  }
  __syncthreads();

  int cur = 0;
  for (int kt = 0; kt < 16; ++kt) {
    if (kt < 15) {                       // issue next K-step's loads first
      const int k1 = kbase + (kt + 1)*64;
      #pragma unroll
      for (int u = 0; u < 4; ++u) {
        int r = wv*32 + u*8 + sr;
        int c = sp ^ (r & 7);
        gload_lds16(&h4c[(size_t)(M0 + r)*16384 + k1 + c*8], &a_s[cur^1][(wv*32 + u*8)*64]);
        gload_lds16(&ewt[(size_t)(N0 + r)*16384 + k1 + c*8], &b_s[cur^1][(wv*32 + u*8)*64]);
      }
    }
    #pragma unroll
    for (int ks = 0; ks < 2; ++ks) {
      bf16x8 af[4], bf[4];
      #pragma unroll
      for (int mt = 0; mt < 4; ++mt) {
        int r = mrow0 + mt*16 + row16;
        int p = (ks*4 + quad) ^ (r & 7);
        af[mt] = *(const bf16x8*)&a_s[cur][r*64 + p*8];
      }
      #pragma unroll
      for (int nt = 0; nt < 4; ++nt) {
        int r = ncol0 + nt*16 + row16;
        int p = (ks*4 + quad) ^ (r & 7);
        bf[nt] = *(const bf16x8*)&b_s[cur][r*64 + p*8];
      }
      #pragma unroll
      for (int mt = 0; mt < 4; ++mt)
        #pragma unroll
        for (int nt = 0; nt < 4; ++nt)
          acc[mt][nt] = __builtin_amdgcn_mfma_f32_16x16x32_bf16(af[mt], bf[nt], acc[mt][nt], 0, 0, 0);
    }
    __syncthreads();   // drains this iter's gloads (next buf ready) + all ds_reads
    cur ^= 1;
  }
  #pragma unroll
  for (int mt = 0; mt < 4; ++mt) {
    int mrow = M0 + mrow0 + mt*16 + quad*4;
    #pragma unroll
    for (int nt = 0; nt < 4; ++nt) {
      int col = N0 + ncol0 + nt*16 + row16;
      #pragma unroll
      for (int r = 0; r < 4; ++r)
        atomicAdd(&z0[(size_t)(img_base + mrow + r)*256 + col], acc[mt][nt][r]);
    }
  }
}

// ---------------- post v4: fully-fused MFMA tail, 16 img/block, grid 256;
// weff + gate + pn2 + gn2 staged to LDS. ---------------------------------------
__global__ void __launch_bounds__(256) k_post2(const float* __restrict__ z0,
    const float* __restrict__ enc_b, const float* __restrict__ nfb,
    const ushort* __restrict__ nfwt, const ushort* __restrict__ pjd,
    const ushort* __restrict__ gjd, const ushort* __restrict__ ptb,
    const float* __restrict__ ws, const float* __restrict__ clf_b,
    float* __restrict__ out) {
  __shared__ ushort zin[16*264];   // 8448 B
  __shared__ ushort zS [16*264];   // 8448 B
  __shared__ float  Df [16*264];   // 16896 B (l / blended)
  __shared__ ushort wS [16*264];   // 8448 B
  __shared__ float  weffS[2560];   // 10240 B
  __shared__ float  gateS[256], pnS[256], gnS[256];   // 3072 B
  __shared__ float  z2s[16];
  const int t = threadIdx.x, bx = blockIdx.x;
  const int img0 = bx*16;
  gateS[t] = ws[OFF_GATE + t];
  pnS[t]   = ws[OFF_PN2 + t];
  gnS[t]   = ws[OFF_GN2 + t];
  #pragma unroll
  for (int u = 0; u < 10; ++u)
    weffS[t + u*256] = ws[OFF_WEFF + t + u*256];
  #pragma unroll
  for (int u = 0; u < 16; ++u) {
    int i = t + u*256;
    int im = i >> 8, d = i & 255;
    zin[im*264 + d] = f2bf(z0[(size_t)(img0 + im)*256 + d] + enc_b[d]);
  }
  __syncthreads();

  const int lane = t & 63, w = t >> 6;
  const int quad = lane >> 4, row16 = lane & 15;
  const int n0 = w*64;

  // ---- phase 1: z = zin @ nfw^T + nfb ----
  f32x4 zC[4];
  #pragma unroll
  for (int nt = 0; nt < 4; ++nt) zC[nt] = (f32x4)0.f;
  #pragma unroll
  for (int ks = 0; ks < 8; ++ks) {
    bf16x8 az = *(const bf16x8*)&zin[row16*264 + ks*32 + quad*8];
    #pragma unroll
    for (int nt = 0; nt < 4; ++nt) {
      bf16x8 bw = *(const bf16x8*)&nfwt[(n0 + nt*16 + row16)*256 + ks*32 + quad*8];
      zC[nt] = __builtin_amdgcn_mfma_f32_16x16x32_bf16(az, bw, zC[nt], 0, 0, 0);
    }
  }
  #pragma unroll
  for (int nt = 0; nt < 4; ++nt) {
    int n = n0 + nt*16 + row16;
    float nb = nfb[n];
    #pragma unroll
    for (int r = 0; r < 4; ++r)
      zS[(quad*4 + r)*264 + n] = f2bf(zC[nt][r] + nb);
  }
  __syncthreads();

  {
    int im = t >> 4, jg = t & 15;
    float s = 0.f;
    #pragma unroll
    for (int q = 0; q < 16; ++q) {
      float v = bf2f(zS[im*264 + jg + 16*q]);
      s += v*v;
    }
    #pragma unroll
    for (int off = 8; off; off >>= 1) s += __shfl_xor(s, off, 16);
    if (jg == 0) z2s[im] = s;
  }
  __syncthreads();

  // ---- phase 2: dp/dg = z @ protos^T / grid^T -> logits l ----
  f32x4 dpC[4], dgC[4];
  #pragma unroll
  for (int nt = 0; nt < 4; ++nt) { dpC[nt] = (f32x4)0.f; dgC[nt] = (f32x4)0.f; }
  #pragma unroll
  for (int ks = 0; ks < 8; ++ks) {
    bf16x8 az = *(const bf16x8*)&zS[row16*264 + ks*32 + quad*8];
    #pragma unroll
    for (int nt = 0; nt < 4; ++nt) {
      int j = n0 + nt*16 + row16;
      bf16x8 bp = *(const bf16x8*)&pjd[j*256 + ks*32 + quad*8];
      bf16x8 bg = *(const bf16x8*)&gjd[j*256 + ks*32 + quad*8];
      dpC[nt] = __builtin_amdgcn_mfma_f32_16x16x32_bf16(az, bp, dpC[nt], 0, 0, 0);
      dgC[nt] = __builtin_amdgcn_mfma_f32_16x16x32_bf16(az, bg, dgC[nt], 0, 0, 0);
    }
  }
  {
    float temp = ws[OFF_TEMP];
    #pragma unroll
    for (int nt = 0; nt < 4; ++nt) {
      int j = n0 + nt*16 + row16;
      float pn = pnS[j], gn = gnS[j];
      #pragma unroll
      for (int r = 0; r < 4; ++r) {
        int im = quad*4 + r;
        float z2 = z2s[im];
        float d2p = z2 + pn - 2.f*dpC[nt][r];
        float d2g = z2 + gn - 2.f*dgC[nt][r];
        float l = -(sqrtf(fmaxf(d2p, 0.f)) + sqrtf(fmaxf(d2g, 0.f)))/temp;
        Df[im*264 + j] = l;
      }
    }
  }
  __syncthreads();

  // ---- softmax + gate + renorm -> wS bf16 ----
  {
    int im = t >> 4, jg = t & 15;
    float m = -1e30f;
    #pragma unroll
    for (int q = 0; q < 16; ++q) m = fmaxf(m, Df[im*264 + jg + 16*q]);
    #pragma unroll
    for (int off = 8; off; off >>= 1) m = fmaxf(m, __shfl_xor(m, off, 16));
    float E = 0.f, S = 0.f, ev[16], gv[16];
    #pragma unroll
    for (int q = 0; q < 16; ++q) {
      int j = jg + 16*q;
      float e = expf(Df[im*264 + j] - m);
      float g = gateS[j];
      ev[q] = e; gv[q] = g;
      E += e; S += e*g;
    }
    #pragma unroll
    for (int off = 8; off; off >>= 1) {
      E += __shfl_xor(E, off, 16);
      S += __shfl_xor(S, off, 16);
    }
    float inv = 1.f/(S + 1e-8f*E);
    #pragma unroll
    for (int q = 0; q < 16; ++q)
      wS[im*264 + jg + 16*q] = f2bf(ev[q]*gv[q]*inv);
  }
  __syncthreads();

  // ---- phase 3: blended = w @ protos ----
  f32x4 blC[4];
  #pragma unroll
  for (int nt = 0; nt < 4; ++nt) blC[nt] = (f32x4)0.f;
  #pragma unroll
  for (int ks = 0; ks < 8; ++ks) {
    bf16x8 aw = *(const bf16x8*)&wS[row16*264 + ks*32 + quad*8];
    #pragma unroll
    for (int nt = 0; nt < 4; ++nt) {
      bf16x8 bp = *(const bf16x8*)&ptb[(n0 + nt*16 + row16)*256 + ks*32 + quad*8];
      blC[nt] = __builtin_amdgcn_mfma_f32_16x16x32_bf16(aw, bp, blC[nt], 0, 0, 0);
    }
  }
  #pragma unroll
  for (int nt = 0; nt < 4; ++nt) {
    int d = n0 + nt*16 + row16;
    #pragma unroll
    for (int r = 0; r < 4; ++r)
      Df[(quad*4 + r)*264 + d] = blC[nt][r];
  }
  __syncthreads();

  if (t < 160) {
    int im = t/10, c = t - im*10;
    float s = clf_b[c];
    for (int d = 0; d < 256; ++d)
      s += Df[im*264 + d]*weffS[d*10 + c];
    out[(size_t)(img0 + im)*10 + c] = s;
  }
}

extern "C" void kernel_launch(void* const* d_in, const int* in_sizes, int n_in,
                              void* d_out, int out_size, void* d_ws, size_t ws_size,
                              hipStream_t stream) {
  (void)in_sizes; (void)n_in; (void)out_size; (void)ws_size;
  const float* x      = (const float*)d_in[0];
  const float* c1w    = (const float*)d_in[2];
  const float* c1b    = (const float*)d_in[3];
  const float* c2w    = (const float*)d_in[4];
  const float* c2b    = (const float*)d_in[5];
  const float* c3w    = (const float*)d_in[6];
  const float* c3b    = (const float*)d_in[7];
  const float* c4w    = (const float*)d_in[8];
  const float* c4b    = (const float*)d_in[9];
  const float* encw   = (const float*)d_in[10];
  const float* encb   = (const float*)d_in[11];
  // d_in[12..17] dead: softmax over a single node == 1 exactly
  const float* clfw   = (const float*)d_in[18];
  const float* clfb   = (const float*)d_in[19];
  const float* nfw    = (const float*)d_in[20];
  const float* nfb    = (const float*)d_in[21];
  const float* protos = (const float*)d_in[22];
  const float* gridp  = (const float*)d_in[23];
  const float* traw   = (const float*)d_in[24];
  const float* gatel  = (const float*)d_in[25];

  float*  ws   = (float*)d_ws;
  float*  w1t  = ws + OFF_W1T;
  ushort* w2t  = (ushort*)((char*)d_ws + OFF_W2T_BYTES);
  ushort* w3t  = (ushort*)((char*)d_ws + OFF_W3T_BYTES);
  ushort* w4t  = (ushort*)((char*)d_ws + OFF_W4T_BYTES);
  ushort* ewt  = (ushort*)((char*)d_ws + OFF_EWT_BYTES);
  ushort* nfwt = (ushort*)((char*)d_ws + OFF_NFWT_BYTES);
  ushort* pjd  = (ushort*)((char*)d_ws + OFF_PJD_BYTES);
  ushort* gjd  = (ushort*)((char*)d_ws + OFF_GJD_BYTES);
  ushort* ptb  = (ushort*)((char*)d_ws + OFF_PTB_BYTES);
  ushort* h4c  = (ushort*)((char*)d_ws + OFF_A_BYTES);
  ushort* h2c  = (ushort*)((char*)d_ws + OFF_B_BYTES);
  float*  z0   = (float*) ((char*)d_ws + OFF_Z0_BYTES);
  float*  out  = (float*)d_out;

  hipLaunchKernelGGL(k_init, dim3(2688), dim3(TPB), 0, stream,
                     encw, ewt, c1w, c2w, c3w, c4w, w1t, w2t, w3t, w4t,
                     protos, gridp, gatel, traw, clfw, ws, z0,
                     nfw, nfwt, pjd, gjd, ptb);
  hipLaunchKernelGGL(k_conv12, dim3(4096), dim3(TPB), 0, stream, x, w1t, c1b, w2t, c2b, h2c);
  for (int c = 0; c < 2; ++c) {
    hipLaunchKernelGGL(k_conv34, dim3(1024), dim3(TPB), 0, stream,
                       h2c, c3b, c4b, w3t, w4t, h4c, c*2048);
    hipLaunchKernelGGL(k_enc, dim3(512), dim3(TPB), 0, stream, h4c, ewt, z0, c*2048);
  }
  hipLaunchKernelGGL(k_post2, dim3(256), dim3(TPB), 0, stream,
                     z0, encb, nfb, nfwt, pjd, gjd, ptb, ws, clfb, out);
}

// Round 11
// 495.226 us; speedup vs baseline: 1.3340x; 1.0479x over previous
//
#include <hip/hip_runtime.h>
#include <math.h>

#define TPB 256

typedef __attribute__((ext_vector_type(8))) short bf16x8;
typedef __attribute__((ext_vector_type(4))) float f32x4;
typedef __attribute__((ext_vector_type(2))) float f32x2;

// ---------------- workspace layout ----------------
// aux (fp32), float offsets:
#define OFF_PN2   0          // 256
#define OFF_GN2   256        // 256
#define OFF_GATE  512        // 256
#define OFF_TEMP  768        // 1
#define OFF_WEFF  1024       // 2560
#define OFF_W1T   3584       // 2400 fp32: w1t[tap<75][oc<32]
// bf16 weight tables (byte offsets):
#define OFF_W2T_BYTES 737280ul    // 9*64*32   bf16
#define OFF_W3T_BYTES 786432ul    // 9*128*64  bf16
#define OFF_W4T_BYTES 983040ul    // 9*256*128 bf16
#define OFF_EWT_BYTES 2097152ul   // ewt[n=256][k=16384] bf16 = 8 MiB
// post-stage bf16 tables:
#define OFF_NFWT_BYTES 10485760ul // nfwt[n=256][k=256] bf16 = 128 KiB
#define OFF_PJD_BYTES  10616832ul // protos[j][d] bf16
#define OFF_GJD_BYTES  10747904ul // grid[j][d] bf16
#define OFF_PTB_BYTES  10878976ul // protosT[d][j] bf16
// big regions (byte offsets):
#define OFF_A_BYTES   12582912ul  // h4c ping buffer: 2048 img x 32KB = 64 MiB
#define OFF_B_BYTES   (OFF_A_BYTES + 67108864ul)   // h2c: 4096 img x 8KB = 32 MiB
                                                   // NOTE: h2c rows of chunk c become
                                                   // DEAD after conv34(c); enc(c) reuses
                                                   // that 16 MiB half as f32 partial buf
                                                   // z0p[c][slice<8][il<2048][n<256].
#define OFF_Z0_BYTES  (OFF_B_BYTES + 33554432ul)   // (now unused)
// total ~112 MiB

// ---------------- bf16 helpers ----------------
__device__ __forceinline__ float bf2f(ushort u) {
  return __uint_as_float(((unsigned)u) << 16);
}
__device__ __forceinline__ ushort f2bf(float f) {   // RNE
  unsigned x = __float_as_uint(f);
  return (ushort)((x + 0x7fffu + ((x >> 16) & 1u)) >> 16);
}
__device__ __forceinline__ unsigned pack2(float a, float b) {
  return (unsigned)f2bf(a) | ((unsigned)f2bf(b) << 16);
}

// async global->LDS, 16B per lane; lds dest = wave-uniform base + lane*16
__device__ __forceinline__ void gload_lds16(const ushort* g, ushort* l) {
  __builtin_amdgcn_global_load_lds(
      (const __attribute__((address_space(1))) unsigned int*)g,
      (__attribute__((address_space(3))) unsigned int*)l, 16, 0, 0);
}

// ---------------- block reductions ----------------
__device__ __forceinline__ float block_sum(float v, float* red) {
  #pragma unroll
  for (int off = 32; off > 0; off >>= 1) v += __shfl_down(v, off, 64);
  int wid = threadIdx.x >> 6;
  __syncthreads();
  if ((threadIdx.x & 63) == 0) red[wid] = v;
  __syncthreads();
  return red[0] + red[1] + red[2] + red[3];
}

// ---------------- k_init: merged setup + prep + prep2 + trans ------------------
// blocks [0,1024):    trans  (enc_w -> ewt bf16 transpose)
// blocks [1024,2176): prep   (conv weight tables)
// blocks [2176,2432): setup  (norms, gate, temp, weff)
// blocks [2432,2688): prep2  (post-stage bf16 tables)
__global__ void __launch_bounds__(256) k_init(
    const float* __restrict__ ew,    ushort* __restrict__ ewt,
    const float* __restrict__ w1,    const float* __restrict__ w2,
    const float* __restrict__ w3,    const float* __restrict__ w4,
    float* __restrict__ w1t, ushort* __restrict__ w2t,
    ushort* __restrict__ w3t, ushort* __restrict__ w4t,
    const float* __restrict__ protos, const float* __restrict__ gridp,
    const float* __restrict__ gate_logits, const float* __restrict__ temp_raw,
    const float* __restrict__ clf_w, float* __restrict__ ws,
    const float* __restrict__ nfw, ushort* __restrict__ nfwt,
    ushort* __restrict__ pjd, ushort* __restrict__ gjd,
    ushort* __restrict__ ptb) {
  __shared__ float tile[64][65];
  __shared__ float red[4];
  const int bx = blockIdx.x, t = threadIdx.x;

  if (bx < 1024) {                 // ---- trans ----
    int kb = bx & 255, nb = bx >> 8;
    #pragma unroll
    for (int i = 0; i < 16; ++i) {
      int idx = t + i*256, k = idx >> 6, n = idx & 63;
      tile[k][n] = ew[(size_t)(kb*64 + k)*256 + nb*64 + n];
    }
    __syncthreads();
    #pragma unroll
    for (int i = 0; i < 16; ++i) {
      int idx = t + i*256, n = idx >> 6, k = idx & 63;
      ewt[(size_t)(nb*64 + n)*16384 + kb*64 + k] = f2bf(tile[k][n]);
    }
    return;
  }
  if (bx < 2176) {                 // ---- prep ----
    int idx = (bx - 1024)*256 + t;
    if (idx < 2400) {
      int tap = idx >> 5, oc = idx & 31;
      w1t[idx] = w1[oc*75 + tap];
    }
    if (idx < 18432) {
      int tap = idx >> 11, r = idx & 2047, oc = r >> 5, ic = r & 31;
      w2t[idx] = f2bf(w2[oc*288 + ic*9 + tap]);
    }
    if (idx < 73728) {
      int tap = idx >> 13, r = idx & 8191, oc = r >> 6, ic = r & 63;
      w3t[idx] = f2bf(w3[oc*576 + ic*9 + tap]);
    }
    if (idx < 294912) {
      int tap = idx >> 15, r = idx & 32767, oc = r >> 7, ic = r & 127;
      w4t[idx] = f2bf(w4[oc*1152 + ic*9 + tap]);
    }
    return;
  }
  if (bx < 2432) {                 // ---- setup ----
    int b = bx - 2176;
    float pv = protos[b*256 + t];
    float gv = gridp [b*256 + t];
    float sp = block_sum(pv*pv, red);
    float sg = block_sum(gv*gv, red);
    if (t == 0) {
      ws[OFF_PN2 + b] = sp;
      ws[OFF_GN2 + b] = sg;
      ws[OFF_GATE + b] = 1.f/(1.f + expf(-gate_logits[b]));
    }
    if (b == 0) {
      for (int i = t; i < 2560; i += TPB) {
        int d = i/10, c = i%10;
        ws[OFF_WEFF + i] = clf_w[d*10+c] + clf_w[(256+d)*10+c]
                         + clf_w[(512+d)*10+c] + clf_w[(768+d)*10+c];
      }
      if (t == 0) {
        float s = 1.f/(1.f + expf(-temp_raw[0]));
        ws[OFF_TEMP] = s*(1.f - 0.001f) + 0.001f;
      }
    }
    return;
  }
  {                                // ---- prep2 ----
    int idx = (bx - 2432)*256 + t;   // 65536
    int a = idx >> 8, b = idx & 255;
    nfwt[idx] = f2bf(nfw[b*256 + a]);     // [n][k] = nfw[k][n]
    pjd [idx] = f2bf(protos[idx]);        // [j][d]
    gjd [idx] = f2bf(gridp[idx]);         // [j][d]
    ptb [idx] = f2bf(protos[b*256 + a]);  // [d][j] = protos[j][d]
  }
}

// ---------------- conv1+conv2 fused v5: x staged to LDS (12.7 KB, pad-33 rows) --
__global__ void __launch_bounds__(256) k_conv12(const float* __restrict__ x,
    const float* __restrict__ w1t, const float* __restrict__ b1,
    const ushort* __restrict__ w2t, const float* __restrict__ b2,
    ushort* __restrict__ h2c) {
  __shared__ ushort xs[17*17*40];   // 23120 B (conv2 input, bf16 packed)
  __shared__ float  xf[3*32*33];    // 12672 B (conv1 input, pad stride 33)
  int b = blockIdx.x, t = threadIdx.x;
  for (int i = t; i < 5780; i += TPB) ((unsigned*)xs)[i] = 0u;
  const float* xb = x + (size_t)b*3072;
  // ---- stage x -> xf: 3 coalesced float4 loads per thread ----
  #pragma unroll
  for (int i = 0; i < 3; ++i) {
    int idx = (t + i*256)*4;                 // 0..3068 step 4, covers 3072 floats
    float4 v = *(const float4*)&xb[idx];
    int ic = idx >> 10, rem = idx & 1023, iy = rem >> 5, ix = rem & 31;
    float* dst = &xf[ic*1056 + iy*33 + ix];
    dst[0] = v.x; dst[1] = v.y; dst[2] = v.z; dst[3] = v.w;
  }
  __syncthreads();

  if (t < 225) {               // conv1: one px per thread, all 32 oc, packed f32
    int oy = t/15, ox = t%15;
    f32x2 acc[16];
    #pragma unroll
    for (int o = 0; o < 16; ++o) acc[o] = *(const f32x2*)&b1[2*o];
    for (int ic = 0; ic < 3; ++ic) {
      const int icb = ic*1056;
      #pragma unroll
      for (int ky = 0; ky < 5; ++ky) {
        int iy = 2*oy - 1 + ky;
        bool rok = (unsigned)iy < 32u;
        int rbase = icb + (rok ? iy*33 : 0);
        #pragma unroll
        for (int kx = 0; kx < 5; ++kx) {
          int ix = 2*ox - 1 + kx;
          bool ok = rok && ((unsigned)ix < 32u);
          float xv = xf[rbase + (ok ? ix : 0)];
          xv = ok ? xv : 0.f;
          f32x2 xv2 = {xv, xv};
          const float* wrow = &w1t[(ic*25 + ky*5 + kx)*32];   // wave-uniform -> s_load
          #pragma unroll
          for (int g = 0; g < 8; ++g) {
            f32x2 wlo = {wrow[4*g+0], wrow[4*g+1]};
            f32x2 whi = {wrow[4*g+2], wrow[4*g+3]};
            acc[2*g]   += xv2*wlo;
            acc[2*g+1] += xv2*whi;
          }
        }
      }
    }
    unsigned pk[16];
    #pragma unroll
    for (int g = 0; g < 16; ++g)
      pk[g] = pack2(fmaxf(acc[g].x, 0.f), fmaxf(acc[g].y, 0.f));
    ushort* cell = &xs[((oy+1)*17 + (ox+1))*40];
    #pragma unroll
    for (int q = 0; q < 4; ++q) *(uint4*)(cell + q*8) = ((uint4*)pk)[q];
  }
  __syncthreads();

  // conv2 MFMA (swapped: oc-in-regs): wave w -> oc [w*16, w*16+16)
  const int lane = t & 63, w = t >> 6;
  const int quad = lane >> 4, row16 = lane & 15;
  f32x4 acc2[4];
  #pragma unroll
  for (int mt = 0; mt < 4; ++mt) acc2[mt] = (f32x4)0.f;
  #pragma unroll
  for (int ky = 0; ky < 3; ++ky)
    #pragma unroll
    for (int kx = 0; kx < 3; ++kx) {
      int tap = ky*3 + kx;
      bf16x8 bf = *(const bf16x8*)&w2t[tap*2048 + (w*16 + row16)*32 + quad*8];
      #pragma unroll
      for (int mt = 0; mt < 4; ++mt) {
        int px = mt*16 + row16;
        int iy = 2*(px >> 3) + ky, ix = 2*(px & 7) + kx;
        bf16x8 af = *(const bf16x8*)&xs[(iy*17 + ix)*40 + quad*8];
        acc2[mt] = __builtin_amdgcn_mfma_f32_16x16x32_bf16(bf, af, acc2[mt], 0, 0, 0);
      }
    }
  float4 bb = *(const float4*)&b2[w*16 + quad*4];
  #pragma unroll
  for (int mt = 0; mt < 4; ++mt) {
    int px = mt*16 + row16;
    uint2 dd;
    dd.x = pack2(fmaxf(acc2[mt][0] + bb.x, 0.f), fmaxf(acc2[mt][1] + bb.y, 0.f));
    dd.y = pack2(fmaxf(acc2[mt][2] + bb.z, 0.f), fmaxf(acc2[mt][3] + bb.w, 0.f));
    *(uint2*)&h2c[(size_t)b*4096 + px*64 + w*16 + quad*4] = dd;
  }
}

// ---------------- conv3+conv4 fused v12 (PROVEN 115us): v9 structure + ping fix.
// 256 thr, 4 waves, 2 img/block, launch_bounds(256,2) -> 256-reg budget
// (124 arch + 128 acc, NO spill), halo-in-LDS (10x10 rows, zeroed ring,
// strides 72/136), depth-1 weight prefetch with 16/32 MFMA per step.
// conv4 writes h4c PING rows [0,2048): ig = bl*2 + img.
__global__ void __launch_bounds__(256, 2) k_conv34(const ushort* __restrict__ h2c,
    const float* __restrict__ b3, const float* __restrict__ b4,
    const ushort* __restrict__ w3t, const ushort* __restrict__ w4t,
    ushort* __restrict__ h4c, int img_base) {
  // xp  = [img<2][row<100][72]   (14400 ushorts, 28.8 KB)  -- conv3 input
  // h3p = [img<2][row<100][136]  (27200 ushorts, 54.4 KB)  -- aliased, conv4 input
  __shared__ __attribute__((aligned(16))) ushort buf[27200];
  ushort* xp  = buf;
  ushort* h3p = buf;
  const int bl = blockIdx.x, t = threadIdx.x;

  // ---- zero xp halo ring: 2 img x 36 rows x 9 uint4 ----
  for (int i = t; i < 648; i += 256) {
    int img = (i >= 324), r = i - img*324;
    int row = r/9, c = r - row*9;
    int rr = (row < 20) ? ((row < 10) ? row : row + 80)
                        : (((row-20) >> 1) + 1)*10 + ((row-20) & 1)*9;
    *(uint4*)&xp[img*7200 + rr*72 + c*8] = (uint4){0,0,0,0};
  }
  // ---- stage conv3 input interior (disjoint from ring; no barrier needed) ----
  #pragma unroll
  for (int u = 0; u < 4; ++u) {
    int i = t + u*256;
    int img = i >> 9, px = (i >> 3) & 63, icg = i & 7;
    bf16x8 v = *(const bf16x8*)&h2c[(size_t)(img_base + bl*2 + img)*4096 + px*64 + icg*8];
    int row = ((px >> 3) + 1)*10 + (px & 7) + 1;
    *(bf16x8*)&xp[img*7200 + row*72 + icg*8] = v;
  }
  __syncthreads();

  const int lane = t & 63, w = t >> 6;
  const int quad = lane >> 4, row16 = lane & 15;

  // per-mt LDS base offsets (ushort units); mt = img*4 + px-group
  int b3off[8], b4off[8], r11c[8];
  #pragma unroll
  for (int mt = 0; mt < 8; ++mt) {
    int px = (mt & 3)*16 + row16;
    int r00 = (px >> 3)*10 + (px & 7);     // halo-corner row for tap (0,0)
    int img = mt >> 2;
    b3off[mt] = img*7200  + r00*72  + quad*8;
    b4off[mt] = img*13600 + r00*136 + quad*8;
    r11c[mt]  = img*13600 + (r00 + 11)*136;   // interior row for epilogue
  }

  // ---- conv3: wave = 32 oc (w*32, 2 frags) x 8 mt (2 img x 64 px) ----
  const int ocb3 = w*32;
  f32x4 c3[8][2];
  #pragma unroll
  for (int mt = 0; mt < 8; ++mt) { c3[mt][0] = (f32x4)0.f; c3[mt][1] = (f32x4)0.f; }
  const ushort* w3b = w3t + (ocb3 + row16)*64 + quad*8;
  bf16x8 wa0 = *(const bf16x8*)(w3b);          // (tap0, ks0), oc-lo 16
  bf16x8 wa1 = *(const bf16x8*)(w3b + 1024);   // oc-hi 16
  #pragma unroll
  for (int tap = 0; tap < 9; ++tap) {
    const int t72 = ((tap/3)*10 + (tap%3))*72;     // compile-time after unroll
    #pragma unroll
    for (int ks = 0; ks < 2; ++ks) {
      // depth-1 weight prefetch; tap==8 overshoot reads workspace gap (discarded)
      const ushort* wn = w3b + ((ks == 0) ? (tap*8192 + 32) : ((tap+1)*8192));
      bf16x8 n0 = *(const bf16x8*)(wn);
      bf16x8 n1 = *(const bf16x8*)(wn + 1024);
      #pragma unroll
      for (int mt = 0; mt < 8; ++mt) {
        bf16x8 af = *(const bf16x8*)&xp[b3off[mt] + t72 + ks*32];
        c3[mt][0] = __builtin_amdgcn_mfma_f32_16x16x32_bf16(wa0, af, c3[mt][0], 0, 0, 0);
        c3[mt][1] = __builtin_amdgcn_mfma_f32_16x16x32_bf16(wa1, af, c3[mt][1], 0, 0, 0);
      }
      wa0 = n0; wa1 = n1;
    }
  }
  __syncthreads();   // ALIAS BARRIER: all xp reads done before h3p overwrites buf

  // ---- zero h3p halo ring: 2 img x 36 rows x 17 uint4 (disjoint from interior) ----
  for (int i = t; i < 1224; i += 256) {
    int img2 = (i >= 612), r = i - img2*612;
    int row = r/17, c = r - row*17;
    int rr = (row < 20) ? ((row < 10) ? row : row + 80)
                        : (((row-20) >> 1) + 1)*10 + ((row-20) & 1)*9;
    *(uint4*)&h3p[img2*13600 + rr*136 + c*8] = (uint4){0,0,0,0};
  }
  // ---- conv3 epilogue: D col=px(row16), row=oc(quad*4+r) -> h3p interior ----
  #pragma unroll
  for (int nt = 0; nt < 2; ++nt) {
    float4 bb = *(const float4*)&b3[ocb3 + nt*16 + quad*4];
    #pragma unroll
    for (int mt = 0; mt < 8; ++mt) {
      uint2 dd;
      dd.x = pack2(fmaxf(c3[mt][nt][0] + bb.x, 0.f), fmaxf(c3[mt][nt][1] + bb.y, 0.f));
      dd.y = pack2(fmaxf(c3[mt][nt][2] + bb.z, 0.f), fmaxf(c3[mt][nt][3] + bb.w, 0.f));
      *(uint2*)&h3p[r11c[mt] + ocb3 + nt*16 + quad*4] = dd;
    }
  }
  __syncthreads();

  // ---- conv4: wave = 64 oc (w*64, 4 frags) x 8 mt (2 img x 64 px) ----
  const int ocb4 = w*64;
  f32x4 c4[8][4];
  #pragma unroll
  for (int mt = 0; mt < 8; ++mt)
    #pragma unroll
    for (int nt = 0; nt < 4; ++nt) c4[mt][nt] = (f32x4)0.f;
  const ushort* w4b = w4t + (ocb4 + row16)*128 + quad*8;
  bf16x8 r4[4];
  #pragma unroll
  for (int nt = 0; nt < 4; ++nt) r4[nt] = *(const bf16x8*)(w4b + nt*2048);
  #pragma unroll
  for (int tap = 0; tap < 9; ++tap) {
    const int t136 = ((tap/3)*10 + (tap%3))*136;
    #pragma unroll
    for (int ks = 0; ks < 4; ++ks) {
      // depth-1 prefetch of next step's 4 weight frags; tap==8 overshoot in gap
      const ushort* wn = w4b + ((ks < 3) ? (tap*32768 + (ks+1)*32) : ((tap+1)*32768));
      bf16x8 nx[4];
      #pragma unroll
      for (int nt = 0; nt < 4; ++nt) nx[nt] = *(const bf16x8*)(wn + nt*2048);
      #pragma unroll
      for (int mt = 0; mt < 8; ++mt) {
        bf16x8 ax = *(const bf16x8*)&h3p[b4off[mt] + t136 + ks*32];
        #pragma unroll
        for (int nt = 0; nt < 4; ++nt)
          c4[mt][nt] = __builtin_amdgcn_mfma_f32_16x16x32_bf16(ax, r4[nt], c4[mt][nt], 0, 0, 0);
      }
      #pragma unroll
      for (int nt = 0; nt < 4; ++nt) r4[nt] = nx[nt];
    }
  }
  // ---- conv4 epilogue: D col=oc(row16), row=px(quad*4+r) -> h4c PING rows ----
  #pragma unroll
  for (int nt = 0; nt < 4; ++nt) {
    int oc = ocb4 + nt*16 + row16;
    float bv = b4[oc];
    #pragma unroll
    for (int mt = 0; mt < 8; ++mt) {
      int ig = bl*2 + (mt >> 2);             // ping-buffer row [0,2048)
      int px0 = (mt & 3)*16 + quad*4;
      uint2 dd;
      dd.x = pack2(fmaxf(c4[mt][nt][0] + bv, 0.f), fmaxf(c4[mt][nt][1] + bv, 0.f));
      dd.y = pack2(fmaxf(c4[mt][nt][2] + bv, 0.f), fmaxf(c4[mt][nt][3] + bv, 0.f));
      *(uint2*)&h4c[(size_t)ig*16384 + oc*64 + px0] = dd;
    }
  }
}

// ---------------- enc v3: NO ATOMICS. Split-K=8 (kt=32), grid 256 x 512 thr
// (8 waves/block, 8 waves/CU — same residency as v2's 2x4-wave blocks).
// Per block: (slice, 128 img, 128 col) partial accumulated fully in regs, then
// written ONCE (plain f32 stores) into z0p = the DEAD h2c half of this chunk
// (h2c rows of chunk c are dead after conv34(c); 16 MiB = 8x2048x256 f32 exactly).
// post2 reduces the 8 slices during its zin staging. Double-buffered LDS +
// XOR-swizzled staging kept from v2. -------------------------------------------
__global__ void __launch_bounds__(512) k_enc(const ushort* __restrict__ h4c,
    const ushort* __restrict__ ewt, float* __restrict__ z0p) {
  __shared__ ushort a_s[2][128*64];   // 32 KB
  __shared__ ushort b_s[2][128*64];   // 32 KB
  const int t = threadIdx.x, bid = blockIdx.x;
  const int slice = bid & 7;           // [0,8)
  const int mb    = (bid >> 3) & 15;   // [0,16)
  const int nb    = bid >> 7;          // [0,2)
  const int M0 = mb*128, N0 = nb*128;
  const int kbase = slice*2048;
  const int lane = t & 63, wv = t >> 6;          // wv in [0,8)
  const int quad = lane >> 4, row16 = lane & 15;
  const int mrow0 = (wv & 3)*32, ncol0 = (wv >> 2)*64;
  const int sr = lane >> 3, sp = lane & 7;

  f32x4 acc[2][4];
  #pragma unroll
  for (int mt = 0; mt < 2; ++mt)
    #pragma unroll
    for (int nt = 0; nt < 4; ++nt) acc[mt][nt] = (f32x4)0.f;

  // prologue: stage kt=0 into buffer 0 (each wave stages 16 rows of A and B)
  #pragma unroll
  for (int u = 0; u < 2; ++u) {
    int r = wv*16 + u*8 + sr;
    int c = sp ^ (r & 7);
    gload_lds16(&h4c[(size_t)(M0 + r)*16384 + kbase + c*8], &a_s[0][(wv*16 + u*8)*64]);
    gload_lds16(&ewt[(size_t)(N0 + r)*16384 + kbase + c*8], &b_s[0][(wv*16 + u*8)*64]);
  }
  __syncthreads();

  int cur = 0;
  for (int kt = 0; kt < 32; ++kt) {
    if (kt < 31) {                       // issue next K-step's loads first
      const int k1 = kbase + (kt + 1)*64;
      #pragma unroll
      for (int u = 0; u < 2; ++u) {
        int r = wv*16 + u*8 + sr;
        int c = sp ^ (r & 7);
        gload_lds16(&h4c[(size_t)(M0 + r)*16384 + k1 + c*8], &a_s[cur^1][(wv*16 + u*8)*64]);
        gload_lds16(&ewt[(size_t)(N0 + r)*16384 + k1 + c*8], &b_s[cur^1][(wv*16 + u*8)*64]);
      }
    }
    #pragma unroll
    for (int ks = 0; ks < 2; ++ks) {
      bf16x8 af[2], bf[4];
      #pragma unroll
      for (int mt = 0; mt < 2; ++mt) {
        int r = mrow0 + mt*16 + row16;
        int p = (ks*4 + quad) ^ (r & 7);
        af[mt] = *(const bf16x8*)&a_s[cur][r*64 + p*8];
      }
      #pragma unroll
      for (int nt = 0; nt < 4; ++nt) {
        int r = ncol0 + nt*16 + row16;
        int p = (ks*4 + quad) ^ (r & 7);
        bf[nt] = *(const bf16x8*)&b_s[cur][r*64 + p*8];
      }
      #pragma unroll
      for (int mt = 0; mt < 2; ++mt)
        #pragma unroll
        for (int nt = 0; nt < 4; ++nt)
          acc[mt][nt] = __builtin_amdgcn_mfma_f32_16x16x32_bf16(af[mt], bf[nt], acc[mt][nt], 0, 0, 0);
    }
    __syncthreads();   // drains this iter's gloads (next buf ready) + all ds_reads
    cur ^= 1;
  }
  // ---- epilogue: one plain f32 store per output element (no atomics) ----
  #pragma unroll
  for (int mt = 0; mt < 2; ++mt) {
    int il = M0 + mrow0 + mt*16 + quad*4;        // local img row [0,2048)
    #pragma unroll
    for (int nt = 0; nt < 4; ++nt) {
      int col = N0 + ncol0 + nt*16 + row16;
      #pragma unroll
      for (int r = 0; r < 4; ++r)
        z0p[((size_t)slice*2048 + il + r)*256 + col] = acc[mt][nt][r];
    }
  }
}

// ---------------- post v5: zin staging reduces the 8 enc partial slices inline
// (zp = h2c region reinterpreted: [c<2][slice<8][il<2048][n<256] f32);
// weff + gate + pn2 + gn2 staged to LDS. ---------------------------------------
__global__ void __launch_bounds__(256) k_post2(const float* __restrict__ zp,
    const float* __restrict__ enc_b, const float* __restrict__ nfb,
    const ushort* __restrict__ nfwt, const ushort* __restrict__ pjd,
    const ushort* __restrict__ gjd, const ushort* __restrict__ ptb,
    const float* __restrict__ ws, const float* __restrict__ clf_b,
    float* __restrict__ out) {
  __shared__ ushort zin[16*264];   // 8448 B
  __shared__ ushort zS [16*264];   // 8448 B
  __shared__ float  Df [16*264];   // 16896 B (l / blended)
  __shared__ ushort wS [16*264];   // 8448 B
  __shared__ float  weffS[2560];   // 10240 B
  __shared__ float  gateS[256], pnS[256], gnS[256];   // 3072 B
  __shared__ float  z2s[16];
  const int t = threadIdx.x, bx = blockIdx.x;
  const int img0 = bx*16;
  gateS[t] = ws[OFF_GATE + t];
  pnS[t]   = ws[OFF_PN2 + t];
  gnS[t]   = ws[OFF_GN2 + t];
  #pragma unroll
  for (int u = 0; u < 10; ++u)
    weffS[t + u*256] = ws[OFF_WEFF + t + u*256];
  #pragma unroll
  for (int u = 0; u < 16; ++u) {
    int i = t + u*256;
    int im = i >> 8, d = i & 255;
    int img = img0 + im;
    int cc = img >> 11, il = img & 2047;
    const float* zb = zp + (size_t)cc*4194304 + (size_t)il*256 + d;
    float s = enc_b[d];
    #pragma unroll
    for (int s8 = 0; s8 < 8; ++s8) s += zb[(size_t)s8*524288];
    zin[im*264 + d] = f2bf(s);
  }
  __syncthreads();

  const int lane = t & 63, w = t >> 6;
  const int quad = lane >> 4, row16 = lane & 15;
  const int n0 = w*64;

  // ---- phase 1: z = zin @ nfw^T + nfb ----
  f32x4 zC[4];
  #pragma unroll
  for (int nt = 0; nt < 4; ++nt) zC[nt] = (f32x4)0.f;
  #pragma unroll
  for (int ks = 0; ks < 8; ++ks) {
    bf16x8 az = *(const bf16x8*)&zin[row16*264 + ks*32 + quad*8];
    #pragma unroll
    for (int nt = 0; nt < 4; ++nt) {
      bf16x8 bw = *(const bf16x8*)&nfwt[(n0 + nt*16 + row16)*256 + ks*32 + quad*8];
      zC[nt] = __builtin_amdgcn_mfma_f32_16x16x32_bf16(az, bw, zC[nt], 0, 0, 0);
    }
  }
  #pragma unroll
  for (int nt = 0; nt < 4; ++nt) {
    int n = n0 + nt*16 + row16;
    float nb = nfb[n];
    #pragma unroll
    for (int r = 0; r < 4; ++r)
      zS[(quad*4 + r)*264 + n] = f2bf(zC[nt][r] + nb);
  }
  __syncthreads();

  {
    int im = t >> 4, jg = t & 15;
    float s = 0.f;
    #pragma unroll
    for (int q = 0; q < 16; ++q) {
      float v = bf2f(zS[im*264 + jg + 16*q]);
      s += v*v;
    }
    #pragma unroll
    for (int off = 8; off; off >>= 1) s += __shfl_xor(s, off, 16);
    if (jg == 0) z2s[im] = s;
  }
  __syncthreads();

  // ---- phase 2: dp/dg = z @ protos^T / grid^T -> logits l ----
  f32x4 dpC[4], dgC[4];
  #pragma unroll
  for (int nt = 0; nt < 4; ++nt) { dpC[nt] = (f32x4)0.f; dgC[nt] = (f32x4)0.f; }
  #pragma unroll
  for (int ks = 0; ks < 8; ++ks) {
    bf16x8 az = *(const bf16x8*)&zS[row16*264 + ks*32 + quad*8];
    #pragma unroll
    for (int nt = 0; nt < 4; ++nt) {
      int j = n0 + nt*16 + row16;
      bf16x8 bp = *(const bf16x8*)&pjd[j*256 + ks*32 + quad*8];
      bf16x8 bg = *(const bf16x8*)&gjd[j*256 + ks*32 + quad*8];
      dpC[nt] = __builtin_amdgcn_mfma_f32_16x16x32_bf16(az, bp, dpC[nt], 0, 0, 0);
      dgC[nt] = __builtin_amdgcn_mfma_f32_16x16x32_bf16(az, bg, dgC[nt], 0, 0, 0);
    }
  }
  {
    float temp = ws[OFF_TEMP];
    #pragma unroll
    for (int nt = 0; nt < 4; ++nt) {
      int j = n0 + nt*16 + row16;
      float pn = pnS[j], gn = gnS[j];
      #pragma unroll
      for (int r = 0; r < 4; ++r) {
        int im = quad*4 + r;
        float z2 = z2s[im];
        float d2p = z2 + pn - 2.f*dpC[nt][r];
        float d2g = z2 + gn - 2.f*dgC[nt][r];
        float l = -(sqrtf(fmaxf(d2p, 0.f)) + sqrtf(fmaxf(d2g, 0.f)))/temp;
        Df[im*264 + j] = l;
      }
    }
  }
  __syncthreads();

  // ---- softmax + gate + renorm -> wS bf16 ----
  {
    int im = t >> 4, jg = t & 15;
    float m = -1e30f;
    #pragma unroll
    for (int q = 0; q < 16; ++q) m = fmaxf(m, Df[im*264 + jg + 16*q]);
    #pragma unroll
    for (int off = 8; off; off >>= 1) m = fmaxf(m, __shfl_xor(m, off, 16));
    float E = 0.f, S = 0.f, ev[16], gv[16];
    #pragma unroll
    for (int q = 0; q < 16; ++q) {
      int j = jg + 16*q;
      float e = expf(Df[im*264 + j] - m);
      float g = gateS[j];
      ev[q] = e; gv[q] = g;
      E += e; S += e*g;
    }
    #pragma unroll
    for (int off = 8; off; off >>= 1) {
      E += __shfl_xor(E, off, 16);
      S += __shfl_xor(S, off, 16);
    }
    float inv = 1.f/(S + 1e-8f*E);
    #pragma unroll
    for (int q = 0; q < 16; ++q)
      wS[im*264 + jg + 16*q] = f2bf(ev[q]*gv[q]*inv);
  }
  __syncthreads();

  // ---- phase 3: blended = w @ protos ----
  f32x4 blC[4];
  #pragma unroll
  for (int nt = 0; nt < 4; ++nt) blC[nt] = (f32x4)0.f;
  #pragma unroll
  for (int ks = 0; ks < 8; ++ks) {
    bf16x8 aw = *(const bf16x8*)&wS[row16*264 + ks*32 + quad*8];
    #pragma unroll
    for (int nt = 0; nt < 4; ++nt) {
      bf16x8 bp = *(const bf16x8*)&ptb[(n0 + nt*16 + row16)*256 + ks*32 + quad*8];
      blC[nt] = __builtin_amdgcn_mfma_f32_16x16x32_bf16(aw, bp, blC[nt], 0, 0, 0);
    }
  }
  #pragma unroll
  for (int nt = 0; nt < 4; ++nt) {
    int d = n0 + nt*16 + row16;
    #pragma unroll
    for (int r = 0; r < 4; ++r)
      Df[(quad*4 + r)*264 + d] = blC[nt][r];
  }
  __syncthreads();

  if (t < 160) {
    int im = t/10, c = t - im*10;
    float s = clf_b[c];
    for (int d = 0; d < 256; ++d)
      s += Df[im*264 + d]*weffS[d*10 + c];
    out[(size_t)(img0 + im)*10 + c] = s;
  }
}

extern "C" void kernel_launch(void* const* d_in, const int* in_sizes, int n_in,
                              void* d_out, int out_size, void* d_ws, size_t ws_size,
                              hipStream_t stream) {
  (void)in_sizes; (void)n_in; (void)out_size; (void)ws_size;
  const float* x      = (const float*)d_in[0];
  const float* c1w    = (const float*)d_in[2];
  const float* c1b    = (const float*)d_in[3];
  const float* c2w    = (const float*)d_in[4];
  const float* c2b    = (const float*)d_in[5];
  const float* c3w    = (const float*)d_in[6];
  const float* c3b    = (const float*)d_in[7];
  const float* c4w    = (const float*)d_in[8];
  const float* c4b    = (const float*)d_in[9];
  const float* encw   = (const float*)d_in[10];
  const float* encb   = (const float*)d_in[11];
  // d_in[12..17] dead: softmax over a single node == 1 exactly
  const float* clfw   = (const float*)d_in[18];
  const float* clfb   = (const float*)d_in[19];
  const float* nfw    = (const float*)d_in[20];
  const float* nfb    = (const float*)d_in[21];
  const float* protos = (const float*)d_in[22];
  const float* gridp  = (const float*)d_in[23];
  const float* traw   = (const float*)d_in[24];
  const float* gatel  = (const float*)d_in[25];

  float*  ws   = (float*)d_ws;
  float*  w1t  = ws + OFF_W1T;
  ushort* w2t  = (ushort*)((char*)d_ws + OFF_W2T_BYTES);
  ushort* w3t  = (ushort*)((char*)d_ws + OFF_W3T_BYTES);
  ushort* w4t  = (ushort*)((char*)d_ws + OFF_W4T_BYTES);
  ushort* ewt  = (ushort*)((char*)d_ws + OFF_EWT_BYTES);
  ushort* nfwt = (ushort*)((char*)d_ws + OFF_NFWT_BYTES);
  ushort* pjd  = (ushort*)((char*)d_ws + OFF_PJD_BYTES);
  ushort* gjd  = (ushort*)((char*)d_ws + OFF_GJD_BYTES);
  ushort* ptb  = (ushort*)((char*)d_ws + OFF_PTB_BYTES);
  ushort* h4c  = (ushort*)((char*)d_ws + OFF_A_BYTES);
  ushort* h2c  = (ushort*)((char*)d_ws + OFF_B_BYTES);
  float*  zp   = (float*) ((char*)d_ws + OFF_B_BYTES);   // partial buf view of h2c
  float*  out  = (float*)d_out;

  hipLaunchKernelGGL(k_init, dim3(2688), dim3(TPB), 0, stream,
                     encw, ewt, c1w, c2w, c3w, c4w, w1t, w2t, w3t, w4t,
                     protos, gridp, gatel, traw, clfw, ws,
                     nfw, nfwt, pjd, gjd, ptb);
  hipLaunchKernelGGL(k_conv12, dim3(4096), dim3(TPB), 0, stream, x, w1t, c1b, w2t, c2b, h2c);
  for (int c = 0; c < 2; ++c) {
    hipLaunchKernelGGL(k_conv34, dim3(1024), dim3(TPB), 0, stream,
                       h2c, c3b, c4b, w3t, w4t, h4c, c*2048);
    // enc writes partials into the now-dead h2c half of this chunk
    hipLaunchKernelGGL(k_enc, dim3(256), dim3(512), 0, stream,
                       h4c, ewt, zp + (size_t)c*4194304);
  }
  hipLaunchKernelGGL(k_post2, dim3(256), dim3(TPB), 0, stream,
                     zp, encb, nfb, nfwt, pjd, gjd, ptb, ws, clfb, out);
}